// Round 10
// baseline (1361.963 us; speedup 1.0000x reference)
//
#include <hip/hip_runtime.h>
#include <hip/hip_bf16.h>

#define HDIM 256
#define NEG_SLOPE 0.2f
#define NB 128          // blocks for hist/scatter
#define SLICES 8        // edge slices per dst in the big-degree aggregator

typedef __attribute__((ext_vector_type(8))) short bf16x8;
typedef __attribute__((ext_vector_type(4))) float f32x4;

__device__ inline ushort f2b(float x) { __hip_bfloat16 h = __float2bfloat16(x); return *(ushort*)&h; }
__device__ inline float b2f(ushort u) { uint x = ((uint)u) << 16; return __int_as_float((int)x); }
__device__ inline void f2sp(float x, ushort& hi, ushort& lo) {
  hi = f2b(x);
  lo = f2b(x - b2f(hi));
}
__device__ inline float sp2f(ushort h, ushort l) { return b2f(h) + b2f(l); }

static inline int cdiv(int a, int b) { return (a + b - 1) / b; }

// ---------------------------------------------------------------- utilities
__global__ void fillf_kernel(float* __restrict__ p, float v, int n) {
  int i = blockIdx.x * blockDim.x + threadIdx.x;
  if (i < n) p[i] = v;
}

// elementwise fp32 -> split hi/lo (same layout)
__global__ void split_kernel(const float* __restrict__ in,
                             ushort* __restrict__ hi, ushort* __restrict__ lo, int n) {
  int i = blockIdx.x * 256 + threadIdx.x;
  if (i >= n) return;
  ushort h, l; f2sp(in[i], h, l);
  hi[i] = h; lo[i] = l;
}

// W[K][N] fp32 -> WT split [N][K] (hi/lo bf16 arrays, transposed)
__global__ void wsplit_kernel(const float* __restrict__ W,
                              ushort* __restrict__ Whi, ushort* __restrict__ Wlo,
                              int K, int N) {
  int i = blockIdx.x * 256 + threadIdx.x;
  if (i >= K * N) return;
  int k = i / N, n = i - k * N;
  ushort h, l; f2sp(W[i], h, l);
  Whi[(size_t)n * K + k] = h;
  Wlo[(size_t)n * K + k] = l;
}

// ---------------------------------------------------------------- direct MFMA GEMM (no LDS, no barriers)
// C = act(A@B + bias). A split [M][K] (or gathered rows), B split [N][K].
// Both A and B fragments are direct 16B global loads matching the MFMA operand
// layout (frag[m or n = lane&15][k = quad*8 + j]). The 4 quads of one instr read
// 4 consecutive 16B pieces of a row -> 16 full 64B lines per wave (coalesced);
// all 4 waves of a block read the same B lines (L1 broadcast). B is L2-resident.
// AMODE: 0 = split A; 2 = gathered split rows (MLP1).
// OUTMODE: 0 fp32 C; 1 split C; 2 fp32 C + bf16(hi) copy Cb.  ACT: 1 = relu.
// Block: 256 thr = 4 waves; wave = 64 rows x 64 cols; block = 256 rows x 64 cols.
// K and N must be multiples of 256 / 64 respectively (true here: K in {256,768,1536}).
template <int AMODE, int OUTMODE, int ACT>
__global__ __launch_bounds__(256) void gemm_da(
    const ushort* __restrict__ Ahi, const ushort* __restrict__ Alo,
    const ushort* __restrict__ xdhi, const ushort* __restrict__ xdlo,
    const ushort* __restrict__ xchi, const ushort* __restrict__ xclo,
    const int* __restrict__ g1, const int* __restrict__ g2, const int* __restrict__ g3,
    int row0,
    const ushort* __restrict__ Bhi, const ushort* __restrict__ Blo,
    const float* __restrict__ bias,
    float* __restrict__ Cf, ushort* __restrict__ Cb,
    ushort* __restrict__ Chi, ushort* __restrict__ Clo,
    int M, int N, int K) {
  const int tid = threadIdx.x;
  const int lane = tid & 63;
  const int w = tid >> 6;
  const int l16 = lane & 15;
  const int quad = lane >> 4;
  const int m0 = blockIdx.y * 256;
  const int n0 = blockIdx.x * 64;

  // B fragment row pointers (cols < N guaranteed: N multiple of 64)
  const ushort* bhp[4];
  const ushort* blp[4];
#pragma unroll
  for (int tn = 0; tn < 4; ++tn) {
    int col = n0 + tn * 16 + l16;
    bhp[tn] = Bhi + (size_t)col * K;
    blp[tn] = Blo + (size_t)col * K;
  }

  // A rows (clamped for load safety; stores are guarded)
  int arow[4];
#pragma unroll
  for (int t = 0; t < 4; ++t) {
    int r = m0 + w * 64 + t * 16 + l16;
    arow[t] = (r < M) ? r : (M - 1);
  }

  f32x4 acc[4][4];
#pragma unroll
  for (int i = 0; i < 4; ++i)
#pragma unroll
    for (int j = 0; j < 4; ++j) acc[i][j] = (f32x4){0.f, 0.f, 0.f, 0.f};

  for (int kc = 0; kc < K; kc += 256) {   // 256-wide K segment (gather granularity)
    const ushort* ahp[4];
    const ushort* alp[4];
    if (AMODE == 2) {
      int seg = kc >> 8;
      const int* g = (seg == 0) ? g1 : (seg == 1 ? g2 : g3);
      const ushort* thi = (seg == 2) ? xchi : xdhi;
      const ushort* tlo = (seg == 2) ? xclo : xdlo;
#pragma unroll
      for (int t = 0; t < 4; ++t) {
        int idx = g[row0 + arow[t]];
        ahp[t] = thi + (size_t)idx * HDIM;
        alp[t] = tlo + (size_t)idx * HDIM;
      }
    } else {
#pragma unroll
      for (int t = 0; t < 4; ++t) {
        ahp[t] = Ahi + (size_t)arow[t] * K + kc;
        alp[t] = Alo + (size_t)arow[t] * K + kc;
      }
    }
#pragma unroll
    for (int k0 = 0; k0 < 256; k0 += 32) {
      bf16x8 ah[4], al[4], bh[4], bl[4];
#pragma unroll
      for (int t = 0; t < 4; ++t) {
        ah[t] = *(const bf16x8*)(ahp[t] + k0 + quad * 8);
        al[t] = *(const bf16x8*)(alp[t] + k0 + quad * 8);
      }
#pragma unroll
      for (int tn = 0; tn < 4; ++tn) {
        bh[tn] = *(const bf16x8*)(bhp[tn] + kc + k0 + quad * 8);
        bl[tn] = *(const bf16x8*)(blp[tn] + kc + k0 + quad * 8);
      }
#pragma unroll
      for (int t = 0; t < 4; ++t)
#pragma unroll
        for (int tn = 0; tn < 4; ++tn) {
          acc[t][tn] = __builtin_amdgcn_mfma_f32_16x16x32_bf16(ah[t], bh[tn], acc[t][tn], 0, 0, 0);
          acc[t][tn] = __builtin_amdgcn_mfma_f32_16x16x32_bf16(ah[t], bl[tn], acc[t][tn], 0, 0, 0);
          acc[t][tn] = __builtin_amdgcn_mfma_f32_16x16x32_bf16(al[t], bh[tn], acc[t][tn], 0, 0, 0);
        }
    }
  }

  // epilogue: C/D layout col=lane&15, row=quad*4+reg
#pragma unroll
  for (int tn = 0; tn < 4; ++tn) {
    int col = n0 + tn * 16 + l16;
    float bv = bias ? bias[col] : 0.f;
#pragma unroll
    for (int t = 0; t < 4; ++t) {
#pragma unroll
      for (int r = 0; r < 4; ++r) {
        int row = m0 + w * 64 + t * 16 + quad * 4 + r;
        if (row >= M) continue;
        float v = acc[t][tn][r] + bv;
        if (ACT == 1) v = fmaxf(v, 0.f);
        if (OUTMODE == 1) {
          ushort h, l; f2sp(v, h, l);
          Chi[(size_t)row * N + col] = h;
          Clo[(size_t)row * N + col] = l;
        } else {
          Cf[(size_t)row * N + col] = v;
          if (OUTMODE == 2) Cb[(size_t)row * N + col] = f2b(v);
        }
      }
    }
  }
}

// ---------------------------------------------------------------- row dots
__global__ __launch_bounds__(256) void rowdot_kernel(
    const float* __restrict__ H, const float* __restrict__ a,
    float* __restrict__ out, int n) {
  int row = blockIdx.x * 4 + (threadIdx.x >> 6);
  if (row >= n) return;
  int lane = threadIdx.x & 63;
  const float* h = H + (size_t)row * HDIM;
  float s = 0.f;
#pragma unroll
  for (int u = 0; u < 4; ++u) {
    int c = lane + u * 64;
    s += h[c] * a[c];
  }
#pragma unroll
  for (int off = 32; off; off >>= 1) s += __shfl_down(s, off);
  if (lane == 0) out[row] = s;
}

__global__ __launch_bounds__(256) void rowdot2_kernel(
    const float* __restrict__ H, const float* __restrict__ a1, const float* __restrict__ a2,
    float* __restrict__ o1, float* __restrict__ o2, int n) {
  int row = blockIdx.x * 4 + (threadIdx.x >> 6);
  if (row >= n) return;
  int lane = threadIdx.x & 63;
  const float* h = H + (size_t)row * HDIM;
  float s1 = 0.f, s2 = 0.f;
#pragma unroll
  for (int u = 0; u < 4; ++u) {
    int c = lane + u * 64;
    float hv = h[c];
    s1 += hv * a1[c];
    s2 += hv * a2[c];
  }
#pragma unroll
  for (int off = 32; off; off >>= 1) {
    s1 += __shfl_down(s1, off);
    s2 += __shfl_down(s2, off);
  }
  if (lane == 0) { o1[row] = s1; o2[row] = s2; }
}

// ---------------------------------------------------------------- counting sort by dst
__global__ __launch_bounds__(256) void hist_kernel(
    const int* __restrict__ src, const int* __restrict__ dst, int E, int nloops,
    int Nd, int* __restrict__ offs) {
  extern __shared__ int bins[];
  int tot = E + nloops;
  int chunk = (tot + NB - 1) / NB;
  int b = blockIdx.x;
  int s0 = b * chunk, s1 = min(s0 + chunk, tot);
  for (int i = threadIdx.x; i < Nd; i += 256) bins[i] = 0;
  __syncthreads();
  for (int i = s0 + threadIdx.x; i < s1; i += 256) {
    int d = (i < E) ? dst[i] : (i - E);
    atomicAdd(&bins[d], 1);
  }
  __syncthreads();
  for (int i = threadIdx.x; i < Nd; i += 256) offs[(size_t)i * NB + b] = bins[i];
}

__global__ __launch_bounds__(256) void scan_bins_kernel(
    int* __restrict__ offs, int* __restrict__ binsum, int Nd) {
  int d = blockIdx.x * 4 + (threadIdx.x >> 6);
  if (d >= Nd) return;
  int lane = threadIdx.x & 63;
  int* p = offs + (size_t)d * NB;
  int v0 = p[2 * lane], v1 = p[2 * lane + 1];
  int s = v0 + v1;
  int t = s;
#pragma unroll
  for (int o = 1; o < 64; o <<= 1) { int u = __shfl_up(t, o); if (lane >= o) t += u; }
  int excl = t - s;
  p[2 * lane] = excl;
  p[2 * lane + 1] = excl + v0;
  if (lane == 63) binsum[d] = t;
}

__global__ __launch_bounds__(256) void scan_base_kernel(
    const int* __restrict__ binsum, int* __restrict__ rowptr, int Nd) {
  __shared__ int wsum[4];
  __shared__ int carry;
  if (threadIdx.x == 0) carry = 0;
  __syncthreads();
  int lane = threadIdx.x & 63, w = threadIdx.x >> 6;
  for (int t0 = 0; t0 < Nd; t0 += 256) {
    int i = t0 + threadIdx.x;
    int v = (i < Nd) ? binsum[i] : 0;
    int t = v;
#pragma unroll
    for (int o = 1; o < 64; o <<= 1) { int u = __shfl_up(t, o); if (lane >= o) t += u; }
    if (lane == 63) wsum[w] = t;
    __syncthreads();
    int add = carry;
    for (int k = 0; k < w; ++k) add += wsum[k];
    if (i < Nd) rowptr[i] = t - v + add;
    __syncthreads();
    if (threadIdx.x == 0) carry += wsum[0] + wsum[1] + wsum[2] + wsum[3];
    __syncthreads();
  }
  if (threadIdx.x == 0) rowptr[Nd] = carry;
}

__global__ __launch_bounds__(256) void scatter_kernel(
    const int* __restrict__ src, const int* __restrict__ dst, int E, int nloops,
    int Nd, const int* __restrict__ offs, const int* __restrict__ rowptr,
    uint* __restrict__ sd) {
  extern __shared__ int bins[];
  int tot = E + nloops;
  int chunk = (tot + NB - 1) / NB;
  int b = blockIdx.x;
  int s0 = b * chunk, s1 = min(s0 + chunk, tot);
  for (int i = threadIdx.x; i < Nd; i += 256) bins[i] = 0;
  __syncthreads();
  for (int i = s0 + threadIdx.x; i < s1; i += 256) {
    int s_, d_;
    if (i < E) { s_ = src[i]; d_ = dst[i]; }
    else       { s_ = d_ = i - E; }
    int local = atomicAdd(&bins[d_], 1);
    int pos = rowptr[d_] + offs[(size_t)d_ * NB + b] + local;
    sd[pos] = (uint)s_ | ((uint)d_ << 16);
  }
}

// ---------------------------------------------------------------- fused GAT edge phase
// wave per dst; x8-batched shuffle-broadcast; writes split output. ACT: 0=l2norm, 1=relu
template <int ACT>
__global__ __launch_bounds__(256) void gat_agg_small(
    const int* __restrict__ rowptr, const uint* __restrict__ sd,
    const float* __restrict__ als, const float* __restrict__ ald,
    const ushort* __restrict__ Hb, const float* __restrict__ bias,
    ushort* __restrict__ Ohi, ushort* __restrict__ Olo, int n) {
  int d = blockIdx.x * 4 + (threadIdx.x >> 6);
  if (d >= n) return;
  int lane = threadIdx.x & 63;
  int r0 = rowptr[d], r1 = rowptr[d + 1];
  float aldd = ald[d];
  float dsum = 0.f;
  for (int j = r0 + lane; j < r1; j += 64) {
    float e = als[sd[j] & 0xffff] + aldd;
    e = (e > 0.f) ? e : NEG_SLOPE * e;
    dsum += __expf(e);
  }
#pragma unroll
  for (int o = 32; o; o >>= 1) dsum += __shfl_xor(dsum, o);
  float rden = 1.f / (dsum + 1e-16f);

  float4 acc = make_float4(0.f, 0.f, 0.f, 0.f);
  for (int b = r0; b < r1; b += 64) {
    int j = b + lane;
    float exv = 0.f; int srcv = 0;
    if (j < r1) {
      uint p = sd[j];
      srcv = p & 0xffff;
      float e = als[srcv] + aldd;
      e = (e > 0.f) ? e : NEG_SLOPE * e;
      exv = __expf(e) * rden;
    }
    int cnt = min(64, r1 - b);
    for (int t0 = 0; t0 < cnt; t0 += 8) {
      float cf[8]; int sv[8];
#pragma unroll
      for (int u = 0; u < 8; ++u) {
        cf[u] = __shfl(exv, t0 + u);
        sv[u] = __shfl(srcv, t0 + u);
      }
      ushort4 hv[8];
#pragma unroll
      for (int u = 0; u < 8; ++u)
        hv[u] = *(const ushort4*)(Hb + (size_t)sv[u] * HDIM + lane * 4);
#pragma unroll
      for (int u = 0; u < 8; ++u) {
        acc.x += cf[u] * b2f(hv[u].x);
        acc.y += cf[u] * b2f(hv[u].y);
        acc.z += cf[u] * b2f(hv[u].z);
        acc.w += cf[u] * b2f(hv[u].w);
      }
    }
  }
  int c = lane * 4;
  float v0 = acc.x + bias[c], v1 = acc.y + bias[c + 1];
  float v2 = acc.z + bias[c + 2], v3 = acc.w + bias[c + 3];
  if (ACT == 1) {
    v0 = fmaxf(v0, 0.f); v1 = fmaxf(v1, 0.f);
    v2 = fmaxf(v2, 0.f); v3 = fmaxf(v3, 0.f);
  } else {
    float ss = v0 * v0 + v1 * v1 + v2 * v2 + v3 * v3;
#pragma unroll
    for (int o = 32; o; o >>= 1) ss += __shfl_xor(ss, o);
    float sc = 1.0f / fmaxf(sqrtf(ss), 1e-12f);
    v0 *= sc; v1 *= sc; v2 *= sc; v3 *= sc;
  }
  ushort h0, l0, h1, l1, h2, l2, h3, l3;
  f2sp(v0, h0, l0); f2sp(v1, h1, l1); f2sp(v2, h2, l2); f2sp(v3, h3, l3);
  *(ushort4*)(Ohi + (size_t)d * HDIM + c) = (ushort4){h0, h1, h2, h3};
  *(ushort4*)(Olo + (size_t)d * HDIM + c) = (ushort4){l0, l1, l2, l3};
}

// high-degree / few-dst graphs (cp): block per (dst, edge-slice); coalesced fp32 atomics.
__global__ __launch_bounds__(256) void gat_agg_slice(
    const int* __restrict__ rowptr, const uint* __restrict__ sd,
    const float* __restrict__ als, const float* __restrict__ ald,
    const ushort* __restrict__ Hb, float* __restrict__ out32, int n) {
  int d = blockIdx.x / SLICES;
  int sl = blockIdx.x - d * SLICES;
  if (d >= n) return;
  int lane = threadIdx.x & 63, w = threadIdx.x >> 6;
  int r0 = rowptr[d], r1 = rowptr[d + 1];
  float aldd = ald[d];
  float dsum = 0.f;
  for (int j = r0 + threadIdx.x; j < r1; j += 256) {
    float e = als[sd[j] & 0xffff] + aldd;
    e = (e > 0.f) ? e : NEG_SLOPE * e;
    dsum += __expf(e);
  }
#pragma unroll
  for (int o = 32; o; o >>= 1) dsum += __shfl_xor(dsum, o);
  __shared__ float wd[4];
  if (lane == 0) wd[w] = dsum;
  __syncthreads();
  float rden = 1.f / (wd[0] + wd[1] + wd[2] + wd[3] + 1e-16f);
  int deg = r1 - r0;
  int per_b = (deg + SLICES - 1) / SLICES;
  int b0 = r0 + sl * per_b, b1 = min(b0 + per_b, r1);
  int wdeg = b1 - b0;
  if (wdeg <= 0) return;
  int per_w = (wdeg + 3) >> 2;
  int w0 = b0 + w * per_w, w1 = min(w0 + per_w, b1);

  float4 acc = make_float4(0.f, 0.f, 0.f, 0.f);
  for (int b = w0; b < w1; b += 64) {
    int j = b + lane;
    float exv = 0.f; int srcv = 0;
    if (j < w1) {
      uint p = sd[j];
      srcv = p & 0xffff;
      float e = als[srcv] + aldd;
      e = (e > 0.f) ? e : NEG_SLOPE * e;
      exv = __expf(e) * rden;
    }
    int cnt = min(64, w1 - b);
    for (int t0 = 0; t0 < cnt; t0 += 8) {
      float cf[8]; int sv[8];
#pragma unroll
      for (int u = 0; u < 8; ++u) {
        cf[u] = __shfl(exv, t0 + u);
        sv[u] = __shfl(srcv, t0 + u);
      }
      ushort4 hv[8];
#pragma unroll
      for (int u = 0; u < 8; ++u)
        hv[u] = *(const ushort4*)(Hb + (size_t)sv[u] * HDIM + lane * 4);
#pragma unroll
      for (int u = 0; u < 8; ++u) {
        acc.x += cf[u] * b2f(hv[u].x);
        acc.y += cf[u] * b2f(hv[u].y);
        acc.z += cf[u] * b2f(hv[u].z);
        acc.w += cf[u] * b2f(hv[u].w);
      }
    }
  }
  float* o = out32 + (size_t)d * HDIM + lane * 4;
  atomicAdd(o + 0, acc.x); atomicAdd(o + 1, acc.y);
  atomicAdd(o + 2, acc.z); atomicAdd(o + 3, acc.w);
}

__global__ void finish_relu_sp(const float* __restrict__ acc, const float* __restrict__ bias,
                               ushort* __restrict__ ohi, ushort* __restrict__ olo, int total) {
  int i = blockIdx.x * blockDim.x + threadIdx.x;
  if (i >= total) return;
  int c = i & (HDIM - 1);
  float v = fmaxf(acc[i] + bias[c], 0.f);
  ushort h, l; f2sp(v, h, l);
  ohi[i] = h; olo[i] = l;
}

// ---------------------------------------------------------------- head
__global__ __launch_bounds__(256) void l2norm_sp_kernel(
    const ushort* __restrict__ ihi, const ushort* __restrict__ ilo,
    ushort* __restrict__ ohi, ushort* __restrict__ olo, int n) {
  int row = blockIdx.x * 4 + (threadIdx.x >> 6);
  if (row >= n) return;
  int lane = threadIdx.x & 63;
  float v[4];
  float ss = 0.f;
#pragma unroll
  for (int u = 0; u < 4; ++u) {
    int c = lane + u * 64;
    float t = sp2f(ihi[(size_t)row * HDIM + c], ilo[(size_t)row * HDIM + c]);
    v[u] = t;
    ss += t * t;
  }
#pragma unroll
  for (int off = 32; off; off >>= 1) ss += __shfl_xor(ss, off);
  float sc = 1.0f / fmaxf(sqrtf(ss), 1e-12f);
#pragma unroll
  for (int u = 0; u < 4; ++u) {
    int c = lane + u * 64;
    ushort h, l; f2sp(v[u] * sc, h, l);
    ohi[(size_t)row * HDIM + c] = h;
    olo[(size_t)row * HDIM + c] = l;
  }
}

__global__ __launch_bounds__(256) void head3_kernel(
    const float* __restrict__ h2, const float* __restrict__ W3, const float* __restrict__ b3,
    float* __restrict__ out, int M, int K) {
  int i = blockIdx.x * 4 + (threadIdx.x >> 6);
  int lane = threadIdx.x & 63;
  if (i >= M) return;
  float s0 = 0.f, s1 = 0.f;
  for (int k = lane; k < K; k += 64) {
    float h = h2[(size_t)i * K + k];
    s0 += h * W3[k * 2 + 0];
    s1 += h * W3[k * 2 + 1];
  }
#pragma unroll
  for (int off = 32; off; off >>= 1) {
    s0 += __shfl_down(s0, off);
    s1 += __shfl_down(s1, off);
  }
  if (lane == 0) {
    out[(size_t)i * 2 + 0] = s0 + b3[0];
    out[(size_t)i * 2 + 1] = s1 + b3[1];
  }
}

// ---------------------------------------------------------------- host side
static void build_sorted(hipStream_t stream,
                         const int* src, const int* dst, int E, int nloops, int Nd,
                         int* offs, int* binsum, int* rowptr, uint* sd) {
  size_t lds = (size_t)Nd * sizeof(int);
  hist_kernel<<<NB, 256, lds, stream>>>(src, dst, E, nloops, Nd, offs);
  scan_bins_kernel<<<cdiv(Nd, 4), 256, 0, stream>>>(offs, binsum, Nd);
  scan_base_kernel<<<1, 256, 0, stream>>>(binsum, rowptr, Nd);
  scatter_kernel<<<NB, 256, lds, stream>>>(src, dst, E, nloops, Nd, offs, rowptr, sd);
}

struct GatBufs {
  float *Hsrc, *Hdst, *als, *ald, *out32;
  ushort* Hb;
};

static void run_gat(hipStream_t stream,
                    const ushort* Xs_hi, const ushort* Xs_lo, int Ns,
                    const ushort* Xd_hi, const ushort* Xd_lo, int Nd, bool same,
                    const ushort* WThi, const ushort* WTlo,
                    const float* asrc, const float* adst, const float* bias,
                    const uint* sd, const int* rowptr,
                    const GatBufs& b, ushort* out_hi, ushort* out_lo, int act) {
  // H_src = X_src @ W  (fp32 + bf16-hi copy for aggregation)
  {
    dim3 g(HDIM / 64, cdiv(Ns, 256));
    gemm_da<0, 2, 0><<<g, 256, 0, stream>>>(Xs_hi, Xs_lo,
        nullptr, nullptr, nullptr, nullptr, nullptr, nullptr, nullptr, 0,
        WThi, WTlo, nullptr, b.Hsrc, b.Hb, nullptr, nullptr, Ns, HDIM, HDIM);
  }
  if (same) {
    rowdot2_kernel<<<cdiv(Ns, 4), 256, 0, stream>>>(b.Hsrc, asrc, adst, b.als, b.ald, Ns);
  } else {
    dim3 g(HDIM / 64, cdiv(Nd, 256));
    gemm_da<0, 0, 0><<<g, 256, 0, stream>>>(Xd_hi, Xd_lo,
        nullptr, nullptr, nullptr, nullptr, nullptr, nullptr, nullptr, 0,
        WThi, WTlo, nullptr, b.Hdst, nullptr, nullptr, nullptr, Nd, HDIM, HDIM);
    rowdot_kernel<<<cdiv(Ns, 4), 256, 0, stream>>>(b.Hsrc, asrc, b.als, Ns);
    rowdot_kernel<<<cdiv(Nd, 4), 256, 0, stream>>>(b.Hdst, adst, b.ald, Nd);
  }
  if (Nd <= 256) {
    fillf_kernel<<<cdiv(Nd * HDIM, 256), 256, 0, stream>>>(b.out32, 0.f, Nd * HDIM);
    gat_agg_slice<<<Nd * SLICES, 256, 0, stream>>>(rowptr, sd, b.als, b.ald, b.Hb, b.out32, Nd);
    finish_relu_sp<<<cdiv(Nd * HDIM, 256), 256, 0, stream>>>(b.out32, bias, out_hi, out_lo, Nd * HDIM);
  } else if (act == 0) {
    gat_agg_small<0><<<cdiv(Nd, 4), 256, 0, stream>>>(rowptr, sd, b.als, b.ald, b.Hb, bias, out_hi, out_lo, Nd);
  } else {
    gat_agg_small<1><<<cdiv(Nd, 4), 256, 0, stream>>>(rowptr, sd, b.als, b.ald, b.Hb, bias, out_hi, out_lo, Nd);
  }
}

extern "C" void kernel_launch(void* const* d_in, const int* in_sizes, int n_in,
                              void* d_out, int out_size, void* d_ws, size_t ws_size,
                              hipStream_t stream) {
  const float* drug_emb = (const float*)d_in[0];
  const float* prot_emb = (const float*)d_in[1];
  const float* cell_emb = (const float*)d_in[2];
  const float* W_pp = (const float*)d_in[3];
  const float* as_pp = (const float*)d_in[4];
  const float* ad_pp = (const float*)d_in[5];
  const float* b_pp = (const float*)d_in[6];
  const float* W_dp = (const float*)d_in[7];
  const float* as_dp = (const float*)d_in[8];
  const float* ad_dp = (const float*)d_in[9];
  const float* b_dp = (const float*)d_in[10];
  const float* W_cp = (const float*)d_in[11];
  const float* as_cp = (const float*)d_in[12];
  const float* ad_cp = (const float*)d_in[13];
  const float* b_cp = (const float*)d_in[14];
  const float* W1 = (const float*)d_in[15];
  const float* b1 = (const float*)d_in[16];
  const float* W2 = (const float*)d_in[17];
  const float* b2 = (const float*)d_in[18];
  const float* W3 = (const float*)d_in[19];
  const float* b3 = (const float*)d_in[20];
  const int* edge_pp = (const int*)d_in[21];
  const int* edge_dp = (const int*)d_in[22];
  const int* edge_cp = (const int*)d_in[23];
  const int* drug1 = (const int*)d_in[24];
  const int* drug2 = (const int*)d_in[25];
  const int* cellb = (const int*)d_in[26];

  const int ND = in_sizes[0] / HDIM;   // 2000
  const int NP = in_sizes[1] / HDIM;   // 19000
  const int NC = in_sizes[2] / HDIM;   // 100
  const int L = in_sizes[3] / (HDIM * HDIM);  // 2
  const int E_pp = in_sizes[21] / 2;
  const int E_dp = in_sizes[22] / 2;
  const int E_cp = in_sizes[23] / 2;
  const int B = in_sizes[24];          // 8192

  const int* src_pp = edge_pp;          const int* dst_pp = edge_pp + E_pp;
  const int* src_dp = edge_dp;          const int* dst_dp = edge_dp + E_dp;
  const int* src_cp = edge_cp;          const int* dst_cp = edge_cp + E_cp;
  const int tot_pp = E_pp + NP, tot_dp = E_dp, tot_cp = E_cp;

  // ---------------- workspace (~70 MB peak)
  float* ws = (float*)d_ws;
  size_t off = 0;
  auto alloc = [&](size_t n) { float* p = ws + off; off += (n + 3) & ~(size_t)3; return p; };
  auto alloc_sp = [&](size_t n, ushort*& hi, ushort*& lo) {
    float* p = alloc(n); hi = (ushort*)p; lo = hi + n;
  };
  int maxN = NP > ND ? NP : ND; if (NC > maxN) maxN = NC;

  ushort *xp_hi, *xp_lo, *xd_hi, *xd_lo, *xc_hi, *xc_lo;
  ushort *xdn_hi, *xdn_lo, *xcn_hi, *xcn_lo;
  alloc_sp((size_t)NP * HDIM, xp_hi, xp_lo);
  alloc_sp((size_t)ND * HDIM, xd_hi, xd_lo);
  alloc_sp((size_t)NC * HDIM, xc_hi, xc_lo);
  alloc_sp((size_t)ND * HDIM, xdn_hi, xdn_lo);
  alloc_sp((size_t)NC * HDIM, xcn_hi, xcn_lo);
  ushort *WTpp_hi, *WTpp_lo, *WTdp_hi, *WTdp_lo, *WTcp_hi, *WTcp_lo;
  alloc_sp((size_t)L * HDIM * HDIM, WTpp_hi, WTpp_lo);
  alloc_sp((size_t)L * HDIM * HDIM, WTdp_hi, WTdp_lo);
  alloc_sp((size_t)L * HDIM * HDIM, WTcp_hi, WTcp_lo);
  int* binsum = (int*)alloc(maxN);
  int* rp_pp = (int*)alloc(NP + 1);
  int* rp_dp = (int*)alloc(ND + 1);
  int* rp_cp = (int*)alloc(NC + 1);
  uint* sd_pp = (uint*)alloc(tot_pp);
  uint* sd_dp = (uint*)alloc(tot_dp);
  uint* sd_cp = (uint*)alloc(tot_cp);
  float* out32 = alloc((size_t)NC * HDIM);

  // scratch region S: graph bufs <-> offs (sort) <-> MLP bufs
  size_t S0 = off;
  float* Hp = ws + S0;
  float* Hd = Hp + (size_t)NP * HDIM;
  ushort* Hb = (ushort*)(Hd + (size_t)ND * HDIM);          // NP*HDIM ushorts
  float* als = (float*)(Hb + (size_t)NP * HDIM);
  float* ald = als + maxN;
  // MLP overlay (used only after graph phase)
  ushort* W1T_hi = (ushort*)(ws + S0);                     // 768*1536 each
  ushort* W1T_lo = W1T_hi + (size_t)768 * 1536;
  ushort* W2T_hi = W1T_lo + (size_t)768 * 1536;            // 1536*512 each
  ushort* W2T_lo = W2T_hi + (size_t)1536 * 512;
  const int CH = 4096;
  ushort* h1_hi = W2T_lo + (size_t)1536 * 512;             // CH*1536 each
  ushort* h1_lo = h1_hi + (size_t)CH * 1536;
  float* h2 = (float*)(h1_lo + (size_t)CH * 1536);         // CH*512 fp32
  (void)ws_size; (void)n_in; (void)out_size;

  // ---- sort builds (offs overlays S; dead before Hp first written)
  int* offs = (int*)(ws + S0);
  build_sorted(stream, src_pp, dst_pp, E_pp, NP, NP, offs, binsum, rp_pp, sd_pp);
  build_sorted(stream, src_dp, dst_dp, E_dp, 0, ND, offs, binsum, rp_dp, sd_dp);
  build_sorted(stream, src_cp, dst_cp, E_cp, 0, NC, offs, binsum, rp_cp, sd_cp);

  // ---- embeddings -> split hi/lo directly into x* (layer-0 inputs; overwritten by
  //      layer-0 outputs only AFTER the GEMMs that read them have completed)
  split_kernel<<<cdiv(NP * HDIM, 256), 256, 0, stream>>>(prot_emb, xp_hi, xp_lo, NP * HDIM);
  split_kernel<<<cdiv(ND * HDIM, 256), 256, 0, stream>>>(drug_emb, xd_hi, xd_lo, ND * HDIM);
  split_kernel<<<cdiv(NC * HDIM, 256), 256, 0, stream>>>(cell_emb, xc_hi, xc_lo, NC * HDIM);

  // ---- graph weight splits (transposed [N][K])
  for (int l = 0; l < L; ++l) {
    int WOFF = l * HDIM * HDIM;
    wsplit_kernel<<<cdiv(HDIM * HDIM, 256), 256, 0, stream>>>(W_pp + WOFF, WTpp_hi + WOFF, WTpp_lo + WOFF, HDIM, HDIM);
    wsplit_kernel<<<cdiv(HDIM * HDIM, 256), 256, 0, stream>>>(W_dp + WOFF, WTdp_hi + WOFF, WTdp_lo + WOFF, HDIM, HDIM);
    wsplit_kernel<<<cdiv(HDIM * HDIM, 256), 256, 0, stream>>>(W_cp + WOFF, WTcp_hi + WOFF, WTcp_lo + WOFF, HDIM, HDIM);
  }

  GatBufs gb{Hp, Hd, als, ald, out32, Hb};

  for (int l = 0; l < L; ++l) {
    const int WOFF = l * HDIM * HDIM, VOFF = l * HDIM;
    run_gat(stream, xp_hi, xp_lo, NP, nullptr, nullptr, NP, /*same=*/true,
            WTpp_hi + WOFF, WTpp_lo + WOFF, as_pp + VOFF, ad_pp + VOFF, b_pp + VOFF,
            sd_pp, rp_pp, gb, xp_hi, xp_lo, 0);
    run_gat(stream, xp_hi, xp_lo, NP, xd_hi, xd_lo, ND, false,
            WTdp_hi + WOFF, WTdp_lo + WOFF, as_dp + VOFF, ad_dp + VOFF, b_dp + VOFF,
            sd_dp, rp_dp, gb, xd_hi, xd_lo, 1);
    run_gat(stream, xp_hi, xp_lo, NP, xc_hi, xc_lo, NC, false,
            WTcp_hi + WOFF, WTcp_lo + WOFF, as_cp + VOFF, ad_cp + VOFF, b_cp + VOFF,
            sd_cp, rp_cp, gb, xc_hi, xc_lo, 1);
  }

  // ---------------- head
  l2norm_sp_kernel<<<cdiv(ND, 4), 256, 0, stream>>>(xd_hi, xd_lo, xdn_hi, xdn_lo, ND);
  l2norm_sp_kernel<<<cdiv(NC, 4), 256, 0, stream>>>(xc_hi, xc_lo, xcn_hi, xcn_lo, NC);

  wsplit_kernel<<<cdiv(768 * 1536, 256), 256, 0, stream>>>(W1, W1T_hi, W1T_lo, 768, 1536);
  wsplit_kernel<<<cdiv(1536 * 512, 256), 256, 0, stream>>>(W2, W2T_hi, W2T_lo, 1536, 512);

  float* outp = (float*)d_out;
  for (int c0 = 0; c0 < B; c0 += CH) {
    int M = (B - c0) < CH ? (B - c0) : CH;
    {
      dim3 g(1536 / 64, cdiv(M, 256));
      gemm_da<2, 1, 1><<<g, 256, 0, stream>>>(nullptr, nullptr,
          xdn_hi, xdn_lo, xcn_hi, xcn_lo, drug1, drug2, cellb, c0,
          W1T_hi, W1T_lo, b1, nullptr, nullptr, h1_hi, h1_lo, M, 1536, 768);
    }
    {
      dim3 g(512 / 64, cdiv(M, 256));
      gemm_da<0, 0, 1><<<g, 256, 0, stream>>>(h1_hi, h1_lo,
          nullptr, nullptr, nullptr, nullptr, nullptr, nullptr, nullptr, 0,
          W2T_hi, W2T_lo, b2, h2, nullptr, nullptr, nullptr, M, 512, 1536);
    }
    head3_kernel<<<cdiv(M, 4), 256, 0, stream>>>(h2, W3, b3, outp + (size_t)c0 * 2, M, 512);
  }
}

// Round 11
// 1239.573 us; speedup vs baseline: 1.0987x; 1.0987x over previous
//
#include <hip/hip_runtime.h>
#include <hip/hip_bf16.h>

#define HDIM 256
#define NEG_SLOPE 0.2f
#define NB 128          // blocks for hist/scatter
#define SLICES 8        // edge slices per dst in the big-degree aggregator

typedef __attribute__((ext_vector_type(8))) short bf16x8;
typedef __attribute__((ext_vector_type(4))) float f32x4;

__device__ inline ushort f2b(float x) { __hip_bfloat16 h = __float2bfloat16(x); return *(ushort*)&h; }
__device__ inline float b2f(ushort u) { uint x = ((uint)u) << 16; return __int_as_float((int)x); }
__device__ inline void f2sp(float x, ushort& hi, ushort& lo) {
  hi = f2b(x);
  lo = f2b(x - b2f(hi));
}
__device__ inline float sp2f(ushort h, ushort l) { return b2f(h) + b2f(l); }

static inline int cdiv(int a, int b) { return (a + b - 1) / b; }

// ---------------------------------------------------------------- utilities
__global__ void fillf_kernel(float* __restrict__ p, float v, int n) {
  int i = blockIdx.x * blockDim.x + threadIdx.x;
  if (i < n) p[i] = v;
}

// elementwise fp32 -> split hi/lo (same layout)
__global__ void split_kernel(const float* __restrict__ in,
                             ushort* __restrict__ hi, ushort* __restrict__ lo, int n) {
  int i = blockIdx.x * 256 + threadIdx.x;
  if (i >= n) return;
  ushort h, l; f2sp(in[i], h, l);
  hi[i] = h; lo[i] = l;
}

// W[K][N] fp32 -> WT split [N][K] (hi/lo bf16 arrays, transposed)
__global__ void wsplit_kernel(const float* __restrict__ W,
                              ushort* __restrict__ Whi, ushort* __restrict__ Wlo,
                              int K, int N) {
  int i = blockIdx.x * 256 + threadIdx.x;
  if (i >= K * N) return;
  int k = i / N, n = i - k * N;
  ushort h, l; f2sp(W[i], h, l);
  Whi[(size_t)n * K + k] = h;
  Wlo[(size_t)n * K + k] = l;
}

// ---------------------------------------------------------------- direct MFMA GEMM (no LDS)
// C = act(A@B + bias). A split [M][K] (or gathered rows), B split [N][K].
// Fragments are direct 16B global loads matching MFMA operand layout.
// TILING (R11): block = 32 rows x 256 cols, 4 waves (each 64-col strip, 2x4 acc).
//   Graph GEMMs (N=256): grid.x covers M only -> A is fetched from HBM EXACTLY ONCE
//   (R10's 128-col-tiled grid re-read A 4x -> 104 MB FETCH, fetch-bound at 1 TB/s).
//   N>256 (MLP): 1D grid with %8 XCD swizzle so same-A blocks share an XCD's L2.
// AMODE: 0 = split A; 2 = gathered split rows (MLP1).
// OUTMODE: 0 fp32 C; 1 split C; 2 fp32 C + bf16(hi) copy Cb.  ACT: 1 = relu.
// K multiple of 256; N multiple of 256.
template <int AMODE, int OUTMODE, int ACT>
__global__ __launch_bounds__(256) void gemm_dn(
    const ushort* __restrict__ Ahi, const ushort* __restrict__ Alo,
    const ushort* __restrict__ xdhi, const ushort* __restrict__ xdlo,
    const ushort* __restrict__ xchi, const ushort* __restrict__ xclo,
    const int* __restrict__ g1, const int* __restrict__ g2, const int* __restrict__ g3,
    int row0,
    const ushort* __restrict__ Bhi, const ushort* __restrict__ Blo,
    const float* __restrict__ bias,
    float* __restrict__ Cf, ushort* __restrict__ Cb,
    ushort* __restrict__ Chi, ushort* __restrict__ Clo,
    int M, int N, int K) {
  const int lane = threadIdx.x & 63;
  const int w = threadIdx.x >> 6;
  const int l16 = lane & 15;
  const int quad = lane >> 4;

  const int NX = N >> 8;
  const int NY = (M + 31) >> 5;
  int L = blockIdx.x;
  int mb, nb;
  if (NX == 1) { mb = L; nb = 0; }
  else {
    int NYa = NY & ~7;            // full swizzle groups
    int tsw = NX * NYa;
    if (L < tsw) {
      mb = (L / (NX * 8)) * 8 + (L & 7);   // same-mb blocks are 8 apart -> same XCD
      nb = (L >> 3) % NX;
    } else {
      int t = L - tsw;
      int rem = NY - NYa;
      mb = NYa + t % rem;
      nb = t / rem;
    }
  }
  const int m0 = mb * 32;
  const int cb = nb * 256 + w * 64;

  // B fragment row pointers (cols < N guaranteed)
  const ushort* bhp[4];
  const ushort* blp[4];
#pragma unroll
  for (int tn = 0; tn < 4; ++tn) {
    int col = cb + tn * 16 + l16;
    bhp[tn] = Bhi + (size_t)col * K;
    blp[tn] = Blo + (size_t)col * K;
  }

  // A rows (clamped for load safety; stores guarded)
  int arow[2];
#pragma unroll
  for (int t = 0; t < 2; ++t) {
    int r = m0 + t * 16 + l16;
    arow[t] = (r < M) ? r : (M - 1);
  }

  f32x4 acc[2][4];
#pragma unroll
  for (int i = 0; i < 2; ++i)
#pragma unroll
    for (int j = 0; j < 4; ++j) acc[i][j] = (f32x4){0.f, 0.f, 0.f, 0.f};

  for (int kc = 0; kc < K; kc += 256) {   // 256-wide K segment (gather granularity)
    const ushort* ahp[2];
    const ushort* alp[2];
    if (AMODE == 2) {
      int seg = kc >> 8;
      const int* g = (seg == 0) ? g1 : (seg == 1 ? g2 : g3);
      const ushort* thi = (seg == 2) ? xchi : xdhi;
      const ushort* tlo = (seg == 2) ? xclo : xdlo;
#pragma unroll
      for (int t = 0; t < 2; ++t) {
        int idx = g[row0 + arow[t]];
        ahp[t] = thi + (size_t)idx * HDIM;
        alp[t] = tlo + (size_t)idx * HDIM;
      }
    } else {
#pragma unroll
      for (int t = 0; t < 2; ++t) {
        ahp[t] = Ahi + (size_t)arow[t] * K + kc;
        alp[t] = Alo + (size_t)arow[t] * K + kc;
      }
    }
#pragma unroll
    for (int k0 = 0; k0 < 256; k0 += 32) {
      bf16x8 ah[2], al[2], bh[4], bl[4];
#pragma unroll
      for (int t = 0; t < 2; ++t) {
        ah[t] = *(const bf16x8*)(ahp[t] + k0 + quad * 8);
        al[t] = *(const bf16x8*)(alp[t] + k0 + quad * 8);
      }
#pragma unroll
      for (int tn = 0; tn < 4; ++tn) {
        bh[tn] = *(const bf16x8*)(bhp[tn] + kc + k0 + quad * 8);
        bl[tn] = *(const bf16x8*)(blp[tn] + kc + k0 + quad * 8);
      }
#pragma unroll
      for (int t = 0; t < 2; ++t)
#pragma unroll
        for (int tn = 0; tn < 4; ++tn) {
          acc[t][tn] = __builtin_amdgcn_mfma_f32_16x16x32_bf16(ah[t], bh[tn], acc[t][tn], 0, 0, 0);
          acc[t][tn] = __builtin_amdgcn_mfma_f32_16x16x32_bf16(ah[t], bl[tn], acc[t][tn], 0, 0, 0);
          acc[t][tn] = __builtin_amdgcn_mfma_f32_16x16x32_bf16(al[t], bh[tn], acc[t][tn], 0, 0, 0);
        }
    }
  }

  // epilogue: C/D layout col=lane&15, row=quad*4+reg
#pragma unroll
  for (int tn = 0; tn < 4; ++tn) {
    int col = cb + tn * 16 + l16;
    float bv = bias ? bias[col] : 0.f;
#pragma unroll
    for (int t = 0; t < 2; ++t) {
#pragma unroll
      for (int r = 0; r < 4; ++r) {
        int row = m0 + t * 16 + quad * 4 + r;
        if (row >= M) continue;
        float v = acc[t][tn][r] + bv;
        if (ACT == 1) v = fmaxf(v, 0.f);
        if (OUTMODE == 1) {
          ushort h, l; f2sp(v, h, l);
          Chi[(size_t)row * N + col] = h;
          Clo[(size_t)row * N + col] = l;
        } else {
          Cf[(size_t)row * N + col] = v;
          if (OUTMODE == 2) Cb[(size_t)row * N + col] = f2b(v);
        }
      }
    }
  }
}

// ---------------------------------------------------------------- row dots
__global__ __launch_bounds__(256) void rowdot_kernel(
    const float* __restrict__ H, const float* __restrict__ a,
    float* __restrict__ out, int n) {
  int row = blockIdx.x * 4 + (threadIdx.x >> 6);
  if (row >= n) return;
  int lane = threadIdx.x & 63;
  const float* h = H + (size_t)row * HDIM;
  float s = 0.f;
#pragma unroll
  for (int u = 0; u < 4; ++u) {
    int c = lane + u * 64;
    s += h[c] * a[c];
  }
#pragma unroll
  for (int off = 32; off; off >>= 1) s += __shfl_down(s, off);
  if (lane == 0) out[row] = s;
}

__global__ __launch_bounds__(256) void rowdot2_kernel(
    const float* __restrict__ H, const float* __restrict__ a1, const float* __restrict__ a2,
    float* __restrict__ o1, float* __restrict__ o2, int n) {
  int row = blockIdx.x * 4 + (threadIdx.x >> 6);
  if (row >= n) return;
  int lane = threadIdx.x & 63;
  const float* h = H + (size_t)row * HDIM;
  float s1 = 0.f, s2 = 0.f;
#pragma unroll
  for (int u = 0; u < 4; ++u) {
    int c = lane + u * 64;
    float hv = h[c];
    s1 += hv * a1[c];
    s2 += hv * a2[c];
  }
#pragma unroll
  for (int off = 32; off; off >>= 1) {
    s1 += __shfl_down(s1, off);
    s2 += __shfl_down(s2, off);
  }
  if (lane == 0) { o1[row] = s1; o2[row] = s2; }
}

// ---------------------------------------------------------------- counting sort by dst
__global__ __launch_bounds__(256) void hist_kernel(
    const int* __restrict__ src, const int* __restrict__ dst, int E, int nloops,
    int Nd, int* __restrict__ offs) {
  extern __shared__ int bins[];
  int tot = E + nloops;
  int chunk = (tot + NB - 1) / NB;
  int b = blockIdx.x;
  int s0 = b * chunk, s1 = min(s0 + chunk, tot);
  for (int i = threadIdx.x; i < Nd; i += 256) bins[i] = 0;
  __syncthreads();
  for (int i = s0 + threadIdx.x; i < s1; i += 256) {
    int d = (i < E) ? dst[i] : (i - E);
    atomicAdd(&bins[d], 1);
  }
  __syncthreads();
  for (int i = threadIdx.x; i < Nd; i += 256) offs[(size_t)i * NB + b] = bins[i];
}

__global__ __launch_bounds__(256) void scan_bins_kernel(
    int* __restrict__ offs, int* __restrict__ binsum, int Nd) {
  int d = blockIdx.x * 4 + (threadIdx.x >> 6);
  if (d >= Nd) return;
  int lane = threadIdx.x & 63;
  int* p = offs + (size_t)d * NB;
  int v0 = p[2 * lane], v1 = p[2 * lane + 1];
  int s = v0 + v1;
  int t = s;
#pragma unroll
  for (int o = 1; o < 64; o <<= 1) { int u = __shfl_up(t, o); if (lane >= o) t += u; }
  int excl = t - s;
  p[2 * lane] = excl;
  p[2 * lane + 1] = excl + v0;
  if (lane == 63) binsum[d] = t;
}

__global__ __launch_bounds__(256) void scan_base_kernel(
    const int* __restrict__ binsum, int* __restrict__ rowptr, int Nd) {
  __shared__ int wsum[4];
  __shared__ int carry;
  if (threadIdx.x == 0) carry = 0;
  __syncthreads();
  int lane = threadIdx.x & 63, w = threadIdx.x >> 6;
  for (int t0 = 0; t0 < Nd; t0 += 256) {
    int i = t0 + threadIdx.x;
    int v = (i < Nd) ? binsum[i] : 0;
    int t = v;
#pragma unroll
    for (int o = 1; o < 64; o <<= 1) { int u = __shfl_up(t, o); if (lane >= o) t += u; }
    if (lane == 63) wsum[w] = t;
    __syncthreads();
    int add = carry;
    for (int k = 0; k < w; ++k) add += wsum[k];
    if (i < Nd) rowptr[i] = t - v + add;
    __syncthreads();
    if (threadIdx.x == 0) carry += wsum[0] + wsum[1] + wsum[2] + wsum[3];
    __syncthreads();
  }
  if (threadIdx.x == 0) rowptr[Nd] = carry;
}

__global__ __launch_bounds__(256) void scatter_kernel(
    const int* __restrict__ src, const int* __restrict__ dst, int E, int nloops,
    int Nd, const int* __restrict__ offs, const int* __restrict__ rowptr,
    uint* __restrict__ sd) {
  extern __shared__ int bins[];
  int tot = E + nloops;
  int chunk = (tot + NB - 1) / NB;
  int b = blockIdx.x;
  int s0 = b * chunk, s1 = min(s0 + chunk, tot);
  for (int i = threadIdx.x; i < Nd; i += 256) bins[i] = 0;
  __syncthreads();
  for (int i = s0 + threadIdx.x; i < s1; i += 256) {
    int s_, d_;
    if (i < E) { s_ = src[i]; d_ = dst[i]; }
    else       { s_ = d_ = i - E; }
    int local = atomicAdd(&bins[d_], 1);
    int pos = rowptr[d_] + offs[(size_t)d_ * NB + b] + local;
    sd[pos] = (uint)s_ | ((uint)d_ << 16);
  }
}

// ---------------------------------------------------------------- fused GAT edge phase
// wave per dst; x8-batched shuffle-broadcast; writes split output. ACT: 0=l2norm, 1=relu
template <int ACT>
__global__ __launch_bounds__(256) void gat_agg_small(
    const int* __restrict__ rowptr, const uint* __restrict__ sd,
    const float* __restrict__ als, const float* __restrict__ ald,
    const ushort* __restrict__ Hb, const float* __restrict__ bias,
    ushort* __restrict__ Ohi, ushort* __restrict__ Olo, int n) {
  int d = blockIdx.x * 4 + (threadIdx.x >> 6);
  if (d >= n) return;
  int lane = threadIdx.x & 63;
  int r0 = rowptr[d], r1 = rowptr[d + 1];
  float aldd = ald[d];
  float dsum = 0.f;
  for (int j = r0 + lane; j < r1; j += 64) {
    float e = als[sd[j] & 0xffff] + aldd;
    e = (e > 0.f) ? e : NEG_SLOPE * e;
    dsum += __expf(e);
  }
#pragma unroll
  for (int o = 32; o; o >>= 1) dsum += __shfl_xor(dsum, o);
  float rden = 1.f / (dsum + 1e-16f);

  float4 acc = make_float4(0.f, 0.f, 0.f, 0.f);
  for (int b = r0; b < r1; b += 64) {
    int j = b + lane;
    float exv = 0.f; int srcv = 0;
    if (j < r1) {
      uint p = sd[j];
      srcv = p & 0xffff;
      float e = als[srcv] + aldd;
      e = (e > 0.f) ? e : NEG_SLOPE * e;
      exv = __expf(e) * rden;
    }
    int cnt = min(64, r1 - b);
    for (int t0 = 0; t0 < cnt; t0 += 8) {
      float cf[8]; int sv[8];
#pragma unroll
      for (int u = 0; u < 8; ++u) {
        cf[u] = __shfl(exv, t0 + u);
        sv[u] = __shfl(srcv, t0 + u);
      }
      ushort4 hv[8];
#pragma unroll
      for (int u = 0; u < 8; ++u)
        hv[u] = *(const ushort4*)(Hb + (size_t)sv[u] * HDIM + lane * 4);
#pragma unroll
      for (int u = 0; u < 8; ++u) {
        acc.x += cf[u] * b2f(hv[u].x);
        acc.y += cf[u] * b2f(hv[u].y);
        acc.z += cf[u] * b2f(hv[u].z);
        acc.w += cf[u] * b2f(hv[u].w);
      }
    }
  }
  int c = lane * 4;
  float v0 = acc.x + bias[c], v1 = acc.y + bias[c + 1];
  float v2 = acc.z + bias[c + 2], v3 = acc.w + bias[c + 3];
  if (ACT == 1) {
    v0 = fmaxf(v0, 0.f); v1 = fmaxf(v1, 0.f);
    v2 = fmaxf(v2, 0.f); v3 = fmaxf(v3, 0.f);
  } else {
    float ss = v0 * v0 + v1 * v1 + v2 * v2 + v3 * v3;
#pragma unroll
    for (int o = 32; o; o >>= 1) ss += __shfl_xor(ss, o);
    float sc = 1.0f / fmaxf(sqrtf(ss), 1e-12f);
    v0 *= sc; v1 *= sc; v2 *= sc; v3 *= sc;
  }
  ushort h0, l0, h1, l1, h2, l2, h3, l3;
  f2sp(v0, h0, l0); f2sp(v1, h1, l1); f2sp(v2, h2, l2); f2sp(v3, h3, l3);
  *(ushort4*)(Ohi + (size_t)d * HDIM + c) = (ushort4){h0, h1, h2, h3};
  *(ushort4*)(Olo + (size_t)d * HDIM + c) = (ushort4){l0, l1, l2, l3};
}

// high-degree / few-dst graphs (cp): block per (dst, edge-slice); coalesced fp32 atomics.
__global__ __launch_bounds__(256) void gat_agg_slice(
    const int* __restrict__ rowptr, const uint* __restrict__ sd,
    const float* __restrict__ als, const float* __restrict__ ald,
    const ushort* __restrict__ Hb, float* __restrict__ out32, int n) {
  int d = blockIdx.x / SLICES;
  int sl = blockIdx.x - d * SLICES;
  if (d >= n) return;
  int lane = threadIdx.x & 63, w = threadIdx.x >> 6;
  int r0 = rowptr[d], r1 = rowptr[d + 1];
  float aldd = ald[d];
  float dsum = 0.f;
  for (int j = r0 + threadIdx.x; j < r1; j += 256) {
    float e = als[sd[j] & 0xffff] + aldd;
    e = (e > 0.f) ? e : NEG_SLOPE * e;
    dsum += __expf(e);
  }
#pragma unroll
  for (int o = 32; o; o >>= 1) dsum += __shfl_xor(dsum, o);
  __shared__ float wd[4];
  if (lane == 0) wd[w] = dsum;
  __syncthreads();
  float rden = 1.f / (wd[0] + wd[1] + wd[2] + wd[3] + 1e-16f);
  int deg = r1 - r0;
  int per_b = (deg + SLICES - 1) / SLICES;
  int b0 = r0 + sl * per_b, b1 = min(b0 + per_b, r1);
  int wdeg = b1 - b0;
  if (wdeg <= 0) return;
  int per_w = (wdeg + 3) >> 2;
  int w0 = b0 + w * per_w, w1 = min(w0 + per_w, b1);

  float4 acc = make_float4(0.f, 0.f, 0.f, 0.f);
  for (int b = w0; b < w1; b += 64) {
    int j = b + lane;
    float exv = 0.f; int srcv = 0;
    if (j < w1) {
      uint p = sd[j];
      srcv = p & 0xffff;
      float e = als[srcv] + aldd;
      e = (e > 0.f) ? e : NEG_SLOPE * e;
      exv = __expf(e) * rden;
    }
    int cnt = min(64, w1 - b);
    for (int t0 = 0; t0 < cnt; t0 += 8) {
      float cf[8]; int sv[8];
#pragma unroll
      for (int u = 0; u < 8; ++u) {
        cf[u] = __shfl(exv, t0 + u);
        sv[u] = __shfl(srcv, t0 + u);
      }
      ushort4 hv[8];
#pragma unroll
      for (int u = 0; u < 8; ++u)
        hv[u] = *(const ushort4*)(Hb + (size_t)sv[u] * HDIM + lane * 4);
#pragma unroll
      for (int u = 0; u < 8; ++u) {
        acc.x += cf[u] * b2f(hv[u].x);
        acc.y += cf[u] * b2f(hv[u].y);
        acc.z += cf[u] * b2f(hv[u].z);
        acc.w += cf[u] * b2f(hv[u].w);
      }
    }
  }
  float* o = out32 + (size_t)d * HDIM + lane * 4;
  atomicAdd(o + 0, acc.x); atomicAdd(o + 1, acc.y);
  atomicAdd(o + 2, acc.z); atomicAdd(o + 3, acc.w);
}

__global__ void finish_relu_sp(const float* __restrict__ acc, const float* __restrict__ bias,
                               ushort* __restrict__ ohi, ushort* __restrict__ olo, int total) {
  int i = blockIdx.x * blockDim.x + threadIdx.x;
  if (i >= total) return;
  int c = i & (HDIM - 1);
  float v = fmaxf(acc[i] + bias[c], 0.f);
  ushort h, l; f2sp(v, h, l);
  ohi[i] = h; olo[i] = l;
}

// ---------------------------------------------------------------- head
__global__ __launch_bounds__(256) void l2norm_sp_kernel(
    const ushort* __restrict__ ihi, const ushort* __restrict__ ilo,
    ushort* __restrict__ ohi, ushort* __restrict__ olo, int n) {
  int row = blockIdx.x * 4 + (threadIdx.x >> 6);
  if (row >= n) return;
  int lane = threadIdx.x & 63;
  float v[4];
  float ss = 0.f;
#pragma unroll
  for (int u = 0; u < 4; ++u) {
    int c = lane + u * 64;
    float t = sp2f(ihi[(size_t)row * HDIM + c], ilo[(size_t)row * HDIM + c]);
    v[u] = t;
    ss += t * t;
  }
#pragma unroll
  for (int off = 32; off; off >>= 1) ss += __shfl_xor(ss, off);
  float sc = 1.0f / fmaxf(sqrtf(ss), 1e-12f);
#pragma unroll
  for (int u = 0; u < 4; ++u) {
    int c = lane + u * 64;
    ushort h, l; f2sp(v[u] * sc, h, l);
    ohi[(size_t)row * HDIM + c] = h;
    olo[(size_t)row * HDIM + c] = l;
  }
}

__global__ __launch_bounds__(256) void head3_kernel(
    const float* __restrict__ h2, const float* __restrict__ W3, const float* __restrict__ b3,
    float* __restrict__ out, int M, int K) {
  int i = blockIdx.x * 4 + (threadIdx.x >> 6);
  int lane = threadIdx.x & 63;
  if (i >= M) return;
  float s0 = 0.f, s1 = 0.f;
  for (int k = lane; k < K; k += 64) {
    float h = h2[(size_t)i * K + k];
    s0 += h * W3[k * 2 + 0];
    s1 += h * W3[k * 2 + 1];
  }
#pragma unroll
  for (int off = 32; off; off >>= 1) {
    s0 += __shfl_down(s0, off);
    s1 += __shfl_down(s1, off);
  }
  if (lane == 0) {
    out[(size_t)i * 2 + 0] = s0 + b3[0];
    out[(size_t)i * 2 + 1] = s1 + b3[1];
  }
}

// ---------------------------------------------------------------- host side
static void build_sorted(hipStream_t stream,
                         const int* src, const int* dst, int E, int nloops, int Nd,
                         int* offs, int* binsum, int* rowptr, uint* sd) {
  size_t lds = (size_t)Nd * sizeof(int);
  hist_kernel<<<NB, 256, lds, stream>>>(src, dst, E, nloops, Nd, offs);
  scan_bins_kernel<<<cdiv(Nd, 4), 256, 0, stream>>>(offs, binsum, Nd);
  scan_base_kernel<<<1, 256, 0, stream>>>(binsum, rowptr, Nd);
  scatter_kernel<<<NB, 256, lds, stream>>>(src, dst, E, nloops, Nd, offs, rowptr, sd);
}

struct GatBufs {
  float *Hsrc, *Hdst, *als, *ald, *out32;
  ushort* Hb;
};

static inline int gemm_grid(int M, int N) { return (N >> 8) * cdiv(M, 32); }

static void run_gat(hipStream_t stream,
                    const ushort* Xs_hi, const ushort* Xs_lo, int Ns,
                    const ushort* Xd_hi, const ushort* Xd_lo, int Nd, bool same,
                    const ushort* WThi, const ushort* WTlo,
                    const float* asrc, const float* adst, const float* bias,
                    const uint* sd, const int* rowptr,
                    const GatBufs& b, ushort* out_hi, ushort* out_lo, int act) {
  // H_src = X_src @ W  (fp32 + bf16-hi copy for aggregation)
  gemm_dn<0, 2, 0><<<gemm_grid(Ns, HDIM), 256, 0, stream>>>(Xs_hi, Xs_lo,
      nullptr, nullptr, nullptr, nullptr, nullptr, nullptr, nullptr, 0,
      WThi, WTlo, nullptr, b.Hsrc, b.Hb, nullptr, nullptr, Ns, HDIM, HDIM);
  if (same) {
    rowdot2_kernel<<<cdiv(Ns, 4), 256, 0, stream>>>(b.Hsrc, asrc, adst, b.als, b.ald, Ns);
  } else {
    gemm_dn<0, 0, 0><<<gemm_grid(Nd, HDIM), 256, 0, stream>>>(Xd_hi, Xd_lo,
        nullptr, nullptr, nullptr, nullptr, nullptr, nullptr, nullptr, 0,
        WThi, WTlo, nullptr, b.Hdst, nullptr, nullptr, nullptr, Nd, HDIM, HDIM);
    rowdot_kernel<<<cdiv(Ns, 4), 256, 0, stream>>>(b.Hsrc, asrc, b.als, Ns);
    rowdot_kernel<<<cdiv(Nd, 4), 256, 0, stream>>>(b.Hdst, adst, b.ald, Nd);
  }
  if (Nd <= 256) {
    fillf_kernel<<<cdiv(Nd * HDIM, 256), 256, 0, stream>>>(b.out32, 0.f, Nd * HDIM);
    gat_agg_slice<<<Nd * SLICES, 256, 0, stream>>>(rowptr, sd, b.als, b.ald, b.Hb, b.out32, Nd);
    finish_relu_sp<<<cdiv(Nd * HDIM, 256), 256, 0, stream>>>(b.out32, bias, out_hi, out_lo, Nd * HDIM);
  } else if (act == 0) {
    gat_agg_small<0><<<cdiv(Nd, 4), 256, 0, stream>>>(rowptr, sd, b.als, b.ald, b.Hb, bias, out_hi, out_lo, Nd);
  } else {
    gat_agg_small<1><<<cdiv(Nd, 4), 256, 0, stream>>>(rowptr, sd, b.als, b.ald, b.Hb, bias, out_hi, out_lo, Nd);
  }
}

extern "C" void kernel_launch(void* const* d_in, const int* in_sizes, int n_in,
                              void* d_out, int out_size, void* d_ws, size_t ws_size,
                              hipStream_t stream) {
  const float* drug_emb = (const float*)d_in[0];
  const float* prot_emb = (const float*)d_in[1];
  const float* cell_emb = (const float*)d_in[2];
  const float* W_pp = (const float*)d_in[3];
  const float* as_pp = (const float*)d_in[4];
  const float* ad_pp = (const float*)d_in[5];
  const float* b_pp = (const float*)d_in[6];
  const float* W_dp = (const float*)d_in[7];
  const float* as_dp = (const float*)d_in[8];
  const float* ad_dp = (const float*)d_in[9];
  const float* b_dp = (const float*)d_in[10];
  const float* W_cp = (const float*)d_in[11];
  const float* as_cp = (const float*)d_in[12];
  const float* ad_cp = (const float*)d_in[13];
  const float* b_cp = (const float*)d_in[14];
  const float* W1 = (const float*)d_in[15];
  const float* b1 = (const float*)d_in[16];
  const float* W2 = (const float*)d_in[17];
  const float* b2 = (const float*)d_in[18];
  const float* W3 = (const float*)d_in[19];
  const float* b3 = (const float*)d_in[20];
  const int* edge_pp = (const int*)d_in[21];
  const int* edge_dp = (const int*)d_in[22];
  const int* edge_cp = (const int*)d_in[23];
  const int* drug1 = (const int*)d_in[24];
  const int* drug2 = (const int*)d_in[25];
  const int* cellb = (const int*)d_in[26];

  const int ND = in_sizes[0] / HDIM;   // 2000
  const int NP = in_sizes[1] / HDIM;   // 19000
  const int NC = in_sizes[2] / HDIM;   // 100
  const int L = in_sizes[3] / (HDIM * HDIM);  // 2
  const int E_pp = in_sizes[21] / 2;
  const int E_dp = in_sizes[22] / 2;
  const int E_cp = in_sizes[23] / 2;
  const int B = in_sizes[24];          // 8192

  const int* src_pp = edge_pp;          const int* dst_pp = edge_pp + E_pp;
  const int* src_dp = edge_dp;          const int* dst_dp = edge_dp + E_dp;
  const int* src_cp = edge_cp;          const int* dst_cp = edge_cp + E_cp;
  const int tot_pp = E_pp + NP, tot_dp = E_dp, tot_cp = E_cp;

  // ---------------- workspace (~70 MB peak)
  float* ws = (float*)d_ws;
  size_t off = 0;
  auto alloc = [&](size_t n) { float* p = ws + off; off += (n + 3) & ~(size_t)3; return p; };
  auto alloc_sp = [&](size_t n, ushort*& hi, ushort*& lo) {
    float* p = alloc(n); hi = (ushort*)p; lo = hi + n;
  };
  int maxN = NP > ND ? NP : ND; if (NC > maxN) maxN = NC;

  ushort *xp_hi, *xp_lo, *xd_hi, *xd_lo, *xc_hi, *xc_lo;
  ushort *xdn_hi, *xdn_lo, *xcn_hi, *xcn_lo;
  alloc_sp((size_t)NP * HDIM, xp_hi, xp_lo);
  alloc_sp((size_t)ND * HDIM, xd_hi, xd_lo);
  alloc_sp((size_t)NC * HDIM, xc_hi, xc_lo);
  alloc_sp((size_t)ND * HDIM, xdn_hi, xdn_lo);
  alloc_sp((size_t)NC * HDIM, xcn_hi, xcn_lo);
  ushort *WTpp_hi, *WTpp_lo, *WTdp_hi, *WTdp_lo, *WTcp_hi, *WTcp_lo;
  alloc_sp((size_t)L * HDIM * HDIM, WTpp_hi, WTpp_lo);
  alloc_sp((size_t)L * HDIM * HDIM, WTdp_hi, WTdp_lo);
  alloc_sp((size_t)L * HDIM * HDIM, WTcp_hi, WTcp_lo);
  int* binsum = (int*)alloc(maxN);
  int* rp_pp = (int*)alloc(NP + 1);
  int* rp_dp = (int*)alloc(ND + 1);
  int* rp_cp = (int*)alloc(NC + 1);
  uint* sd_pp = (uint*)alloc(tot_pp);
  uint* sd_dp = (uint*)alloc(tot_dp);
  uint* sd_cp = (uint*)alloc(tot_cp);
  float* out32 = alloc((size_t)NC * HDIM);

  // scratch region S: graph bufs <-> offs (sort) <-> MLP bufs
  size_t S0 = off;
  float* Hp = ws + S0;
  float* Hd = Hp + (size_t)NP * HDIM;
  ushort* Hb = (ushort*)(Hd + (size_t)ND * HDIM);          // NP*HDIM ushorts
  float* als = (float*)(Hb + (size_t)NP * HDIM);
  float* ald = als + maxN;
  // MLP overlay (used only after graph phase)
  ushort* W1T_hi = (ushort*)(ws + S0);                     // 768*1536 each
  ushort* W1T_lo = W1T_hi + (size_t)768 * 1536;
  ushort* W2T_hi = W1T_lo + (size_t)768 * 1536;            // 1536*512 each
  ushort* W2T_lo = W2T_hi + (size_t)1536 * 512;
  const int CH = 4096;
  ushort* h1_hi = W2T_lo + (size_t)1536 * 512;             // CH*1536 each
  ushort* h1_lo = h1_hi + (size_t)CH * 1536;
  float* h2 = (float*)(h1_lo + (size_t)CH * 1536);         // CH*512 fp32
  (void)ws_size; (void)n_in; (void)out_size;

  // ---- sort builds (offs overlays S; dead before Hp first written)
  int* offs = (int*)(ws + S0);
  build_sorted(stream, src_pp, dst_pp, E_pp, NP, NP, offs, binsum, rp_pp, sd_pp);
  build_sorted(stream, src_dp, dst_dp, E_dp, 0, ND, offs, binsum, rp_dp, sd_dp);
  build_sorted(stream, src_cp, dst_cp, E_cp, 0, NC, offs, binsum, rp_cp, sd_cp);

  // ---- embeddings -> split hi/lo into x* (layer-0 inputs)
  split_kernel<<<cdiv(NP * HDIM, 256), 256, 0, stream>>>(prot_emb, xp_hi, xp_lo, NP * HDIM);
  split_kernel<<<cdiv(ND * HDIM, 256), 256, 0, stream>>>(drug_emb, xd_hi, xd_lo, ND * HDIM);
  split_kernel<<<cdiv(NC * HDIM, 256), 256, 0, stream>>>(cell_emb, xc_hi, xc_lo, NC * HDIM);

  // ---- graph weight splits (transposed [N][K])
  for (int l = 0; l < L; ++l) {
    int WOFF = l * HDIM * HDIM;
    wsplit_kernel<<<cdiv(HDIM * HDIM, 256), 256, 0, stream>>>(W_pp + WOFF, WTpp_hi + WOFF, WTpp_lo + WOFF, HDIM, HDIM);
    wsplit_kernel<<<cdiv(HDIM * HDIM, 256), 256, 0, stream>>>(W_dp + WOFF, WTdp_hi + WOFF, WTdp_lo + WOFF, HDIM, HDIM);
    wsplit_kernel<<<cdiv(HDIM * HDIM, 256), 256, 0, stream>>>(W_cp + WOFF, WTcp_hi + WOFF, WTcp_lo + WOFF, HDIM, HDIM);
  }

  GatBufs gb{Hp, Hd, als, ald, out32, Hb};

  for (int l = 0; l < L; ++l) {
    const int WOFF = l * HDIM * HDIM, VOFF = l * HDIM;
    run_gat(stream, xp_hi, xp_lo, NP, nullptr, nullptr, NP, /*same=*/true,
            WTpp_hi + WOFF, WTpp_lo + WOFF, as_pp + VOFF, ad_pp + VOFF, b_pp + VOFF,
            sd_pp, rp_pp, gb, xp_hi, xp_lo, 0);
    run_gat(stream, xp_hi, xp_lo, NP, xd_hi, xd_lo, ND, false,
            WTdp_hi + WOFF, WTdp_lo + WOFF, as_dp + VOFF, ad_dp + VOFF, b_dp + VOFF,
            sd_dp, rp_dp, gb, xd_hi, xd_lo, 1);
    run_gat(stream, xp_hi, xp_lo, NP, xc_hi, xc_lo, NC, false,
            WTcp_hi + WOFF, WTcp_lo + WOFF, as_cp + VOFF, ad_cp + VOFF, b_cp + VOFF,
            sd_cp, rp_cp, gb, xc_hi, xc_lo, 1);
  }

  // ---------------- head
  l2norm_sp_kernel<<<cdiv(ND, 4), 256, 0, stream>>>(xd_hi, xd_lo, xdn_hi, xdn_lo, ND);
  l2norm_sp_kernel<<<cdiv(NC, 4), 256, 0, stream>>>(xc_hi, xc_lo, xcn_hi, xcn_lo, NC);

  wsplit_kernel<<<cdiv(768 * 1536, 256), 256, 0, stream>>>(W1, W1T_hi, W1T_lo, 768, 1536);
  wsplit_kernel<<<cdiv(1536 * 512, 256), 256, 0, stream>>>(W2, W2T_hi, W2T_lo, 1536, 512);

  float* outp = (float*)d_out;
  for (int c0 = 0; c0 < B; c0 += CH) {
    int M = (B - c0) < CH ? (B - c0) : CH;
    gemm_dn<2, 1, 1><<<gemm_grid(M, 1536), 256, 0, stream>>>(nullptr, nullptr,
        xdn_hi, xdn_lo, xcn_hi, xcn_lo, drug1, drug2, cellb, c0,
        W1T_hi, W1T_lo, b1, nullptr, nullptr, h1_hi, h1_lo, M, 1536, 768);
    gemm_dn<0, 0, 1><<<gemm_grid(M, 512), 256, 0, stream>>>(h1_hi, h1_lo,
        nullptr, nullptr, nullptr, nullptr, nullptr, nullptr, nullptr, 0,
        W2T_hi, W2T_lo, b2, h2, nullptr, nullptr, nullptr, M, 512, 1536);
    head3_kernel<<<cdiv(M, 4), 256, 0, stream>>>(h2, W3, b3, outp + (size_t)c0 * 2, M, 512);
  }
}

// Round 12
// 1185.970 us; speedup vs baseline: 1.1484x; 1.0452x over previous
//
#include <hip/hip_runtime.h>
#include <hip/hip_bf16.h>

#define HDIM 256
#define NEG_SLOPE 0.2f
#define NB 128          // blocks for hist/scatter
#define SLICES 8        // edge slices per dst in the big-degree aggregator

typedef __attribute__((ext_vector_type(8))) short bf16x8;
typedef __attribute__((ext_vector_type(4))) float f32x4;

__device__ inline ushort f2b(float x) { __hip_bfloat16 h = __float2bfloat16(x); return *(ushort*)&h; }
__device__ inline float b2f(ushort u) { uint x = ((uint)u) << 16; return __int_as_float((int)x); }
__device__ inline void f2sp(float x, ushort& hi, ushort& lo) {
  hi = f2b(x);
  lo = f2b(x - b2f(hi));
}
__device__ inline float sp2f(ushort h, ushort l) { return b2f(h) + b2f(l); }

static inline int cdiv(int a, int b) { return (a + b - 1) / b; }

// ---------------------------------------------------------------- utilities
__global__ void fillf_kernel(float* __restrict__ p, float v, int n) {
  int i = blockIdx.x * blockDim.x + threadIdx.x;
  if (i < n) p[i] = v;
}

// elementwise fp32 -> split hi/lo (same layout)
__global__ void split_kernel(const float* __restrict__ in,
                             ushort* __restrict__ hi, ushort* __restrict__ lo, int n) {
  int i = blockIdx.x * 256 + threadIdx.x;
  if (i >= n) return;
  ushort h, l; f2sp(in[i], h, l);
  hi[i] = h; lo[i] = l;
}

// W[K][N] fp32 -> WT split [N][K] (hi/lo bf16 arrays, transposed)
__global__ void wsplit_kernel(const float* __restrict__ W,
                              ushort* __restrict__ Whi, ushort* __restrict__ Wlo,
                              int K, int N) {
  int i = blockIdx.x * 256 + threadIdx.x;
  if (i >= K * N) return;
  int k = i / N, n = i - k * N;
  ushort h, l; f2sp(W[i], h, l);
  Whi[(size_t)n * K + k] = h;
  Wlo[(size_t)n * K + k] = l;
}

// ---------------------------------------------------------------- direct MFMA GEMM (no LDS staging)
// A split [M][K] (or gathered rows), B split [N][K]; direct 16B fragment loads.
// Block = 32 rows x 256 cols, 4 waves. Graph GEMMs (N=256): A fetched once.
// OUTMODE: 0 fp32 C; 1 split C; 3 bf16 Cb ONLY + fused row-dots (graph src GEMMs,
//          requires N==256 so the block owns full rows); 4 NO C, dots only (dst GEMMs).
// NDOT: 1 -> dot1_out[row] = C[row,:].dota ; 2 -> also dot2_out[row] = C[row,:].dotb
// (R12: H fp32 was written (19.5MB) then read once by rowdot -> 39MB of traffic per
//  NP-GEMM for a 76KB result. Fused epilogue dots delete both.)  ACT: 1 = relu.
template <int AMODE, int OUTMODE, int ACT, int NDOT>
__global__ __launch_bounds__(256) void gemm_dn(
    const ushort* __restrict__ Ahi, const ushort* __restrict__ Alo,
    const ushort* __restrict__ xdhi, const ushort* __restrict__ xdlo,
    const ushort* __restrict__ xchi, const ushort* __restrict__ xclo,
    const int* __restrict__ g1, const int* __restrict__ g2, const int* __restrict__ g3,
    int row0,
    const ushort* __restrict__ Bhi, const ushort* __restrict__ Blo,
    const float* __restrict__ bias,
    const float* __restrict__ dota, const float* __restrict__ dotb,
    float* __restrict__ dot1_out, float* __restrict__ dot2_out,
    float* __restrict__ Cf, ushort* __restrict__ Cb,
    ushort* __restrict__ Chi, ushort* __restrict__ Clo,
    int M, int N, int K) {
  const int lane = threadIdx.x & 63;
  const int w = threadIdx.x >> 6;
  const int l16 = lane & 15;
  const int quad = lane >> 4;

  const int NX = N >> 8;
  const int NY = (M + 31) >> 5;
  int L = blockIdx.x;
  int mb, nb;
  if (NX == 1) { mb = L; nb = 0; }
  else {
    int NYa = NY & ~7;            // full swizzle groups
    int tsw = NX * NYa;
    if (L < tsw) {
      mb = (L / (NX * 8)) * 8 + (L & 7);   // same-mb blocks are 8 apart -> same XCD
      nb = (L >> 3) % NX;
    } else {
      int t = L - tsw;
      int rem = NY - NYa;
      mb = NYa + t % rem;
      nb = t / rem;
    }
  }
  const int m0 = mb * 32;
  const int cb = nb * 256 + w * 64;

  const ushort* bhp[4];
  const ushort* blp[4];
#pragma unroll
  for (int tn = 0; tn < 4; ++tn) {
    int col = cb + tn * 16 + l16;
    bhp[tn] = Bhi + (size_t)col * K;
    blp[tn] = Blo + (size_t)col * K;
  }

  int arow[2];
#pragma unroll
  for (int t = 0; t < 2; ++t) {
    int r = m0 + t * 16 + l16;
    arow[t] = (r < M) ? r : (M - 1);
  }

  f32x4 acc[2][4];
#pragma unroll
  for (int i = 0; i < 2; ++i)
#pragma unroll
    for (int j = 0; j < 4; ++j) acc[i][j] = (f32x4){0.f, 0.f, 0.f, 0.f};

  for (int kc = 0; kc < K; kc += 256) {
    const ushort* ahp[2];
    const ushort* alp[2];
    if (AMODE == 2) {
      int seg = kc >> 8;
      const int* g = (seg == 0) ? g1 : (seg == 1 ? g2 : g3);
      const ushort* thi = (seg == 2) ? xchi : xdhi;
      const ushort* tlo = (seg == 2) ? xclo : xdlo;
#pragma unroll
      for (int t = 0; t < 2; ++t) {
        int idx = g[row0 + arow[t]];
        ahp[t] = thi + (size_t)idx * HDIM;
        alp[t] = tlo + (size_t)idx * HDIM;
      }
    } else {
#pragma unroll
      for (int t = 0; t < 2; ++t) {
        ahp[t] = Ahi + (size_t)arow[t] * K + kc;
        alp[t] = Alo + (size_t)arow[t] * K + kc;
      }
    }
#pragma unroll
    for (int k0 = 0; k0 < 256; k0 += 32) {
      bf16x8 ah[2], al[2], bh[4], bl[4];
#pragma unroll
      for (int t = 0; t < 2; ++t) {
        ah[t] = *(const bf16x8*)(ahp[t] + k0 + quad * 8);
        al[t] = *(const bf16x8*)(alp[t] + k0 + quad * 8);
      }
#pragma unroll
      for (int tn = 0; tn < 4; ++tn) {
        bh[tn] = *(const bf16x8*)(bhp[tn] + kc + k0 + quad * 8);
        bl[tn] = *(const bf16x8*)(blp[tn] + kc + k0 + quad * 8);
      }
#pragma unroll
      for (int t = 0; t < 2; ++t)
#pragma unroll
        for (int tn = 0; tn < 4; ++tn) {
          acc[t][tn] = __builtin_amdgcn_mfma_f32_16x16x32_bf16(ah[t], bh[tn], acc[t][tn], 0, 0, 0);
          acc[t][tn] = __builtin_amdgcn_mfma_f32_16x16x32_bf16(ah[t], bl[tn], acc[t][tn], 0, 0, 0);
          acc[t][tn] = __builtin_amdgcn_mfma_f32_16x16x32_bf16(al[t], bh[tn], acc[t][tn], 0, 0, 0);
        }
    }
  }

  // ---- fused row-dots (OUTMODE 3/4; N==256 so block owns full rows)
  if (OUTMODE == 3 || OUTMODE == 4) {
    float d1[8], d2[8];
#pragma unroll
    for (int i = 0; i < 8; ++i) { d1[i] = 0.f; d2[i] = 0.f; }
#pragma unroll
    for (int tn = 0; tn < 4; ++tn) {
      int col = cb + tn * 16 + l16;
      float a1 = dota[col];
      float a2 = (NDOT == 2) ? dotb[col] : 0.f;
#pragma unroll
      for (int t = 0; t < 2; ++t)
#pragma unroll
        for (int r = 0; r < 4; ++r) {
          float v = acc[t][tn][r];
          d1[t * 4 + r] += v * a1;
          if (NDOT == 2) d2[t * 4 + r] += v * a2;
        }
    }
#pragma unroll
    for (int o = 1; o < 16; o <<= 1) {
#pragma unroll
      for (int i = 0; i < 8; ++i) {
        d1[i] += __shfl_xor(d1[i], o);
        if (NDOT == 2) d2[i] += __shfl_xor(d2[i], o);
      }
    }
    __shared__ float reds[4][32];
    __shared__ float redd[4][32];
    if (l16 == 0) {
#pragma unroll
      for (int t = 0; t < 2; ++t)
#pragma unroll
        for (int r = 0; r < 4; ++r) {
          reds[w][t * 16 + quad * 4 + r] = d1[t * 4 + r];
          if (NDOT == 2) redd[w][t * 16 + quad * 4 + r] = d2[t * 4 + r];
        }
    }
    __syncthreads();
    if (threadIdx.x < 32) {
      int row = m0 + threadIdx.x;
      if (row < M) {
        dot1_out[row] = reds[0][threadIdx.x] + reds[1][threadIdx.x] +
                        reds[2][threadIdx.x] + reds[3][threadIdx.x];
        if (NDOT == 2)
          dot2_out[row] = redd[0][threadIdx.x] + redd[1][threadIdx.x] +
                          redd[2][threadIdx.x] + redd[3][threadIdx.x];
      }
    }
  }

  if (OUTMODE == 4) return;   // dots only, no C

  // ---- C stores: C/D layout col=lane&15, row=quad*4+reg
#pragma unroll
  for (int tn = 0; tn < 4; ++tn) {
    int col = cb + tn * 16 + l16;
    float bv = (OUTMODE == 3) ? 0.f : (bias ? bias[col] : 0.f);
#pragma unroll
    for (int t = 0; t < 2; ++t) {
#pragma unroll
      for (int r = 0; r < 4; ++r) {
        int row = m0 + t * 16 + quad * 4 + r;
        if (row >= M) continue;
        float v = acc[t][tn][r] + bv;
        if (ACT == 1) v = fmaxf(v, 0.f);
        if (OUTMODE == 3) {
          Cb[(size_t)row * N + col] = f2b(v);
        } else if (OUTMODE == 1) {
          ushort h, l; f2sp(v, h, l);
          Chi[(size_t)row * N + col] = h;
          Clo[(size_t)row * N + col] = l;
        } else {
          Cf[(size_t)row * N + col] = v;
        }
      }
    }
  }
}

#define GEMM_ARGS(Ahi, Alo, xdh, xdl, xch, xcl, g1, g2, g3, r0, Bh, Bl, bias, da, db, d1, d2, Cf, Cb, Ch, Cl, M, N, K) \
  Ahi, Alo, xdh, xdl, xch, xcl, g1, g2, g3, r0, Bh, Bl, bias, da, db, d1, d2, Cf, Cb, Ch, Cl, M, N, K

// ---------------------------------------------------------------- counting sort by dst
__global__ __launch_bounds__(256) void hist_kernel(
    const int* __restrict__ src, const int* __restrict__ dst, int E, int nloops,
    int Nd, int* __restrict__ offs) {
  extern __shared__ int bins[];
  int tot = E + nloops;
  int chunk = (tot + NB - 1) / NB;
  int b = blockIdx.x;
  int s0 = b * chunk, s1 = min(s0 + chunk, tot);
  for (int i = threadIdx.x; i < Nd; i += 256) bins[i] = 0;
  __syncthreads();
  for (int i = s0 + threadIdx.x; i < s1; i += 256) {
    int d = (i < E) ? dst[i] : (i - E);
    atomicAdd(&bins[d], 1);
  }
  __syncthreads();
  for (int i = threadIdx.x; i < Nd; i += 256) offs[(size_t)i * NB + b] = bins[i];
}

__global__ __launch_bounds__(256) void scan_bins_kernel(
    int* __restrict__ offs, int* __restrict__ binsum, int Nd) {
  int d = blockIdx.x * 4 + (threadIdx.x >> 6);
  if (d >= Nd) return;
  int lane = threadIdx.x & 63;
  int* p = offs + (size_t)d * NB;
  int v0 = p[2 * lane], v1 = p[2 * lane + 1];
  int s = v0 + v1;
  int t = s;
#pragma unroll
  for (int o = 1; o < 64; o <<= 1) { int u = __shfl_up(t, o); if (lane >= o) t += u; }
  int excl = t - s;
  p[2 * lane] = excl;
  p[2 * lane + 1] = excl + v0;
  if (lane == 63) binsum[d] = t;
}

__global__ __launch_bounds__(256) void scan_base_kernel(
    const int* __restrict__ binsum, int* __restrict__ rowptr, int Nd) {
  __shared__ int wsum[4];
  __shared__ int carry;
  if (threadIdx.x == 0) carry = 0;
  __syncthreads();
  int lane = threadIdx.x & 63, w = threadIdx.x >> 6;
  for (int t0 = 0; t0 < Nd; t0 += 256) {
    int i = t0 + threadIdx.x;
    int v = (i < Nd) ? binsum[i] : 0;
    int t = v;
#pragma unroll
    for (int o = 1; o < 64; o <<= 1) { int u = __shfl_up(t, o); if (lane >= o) t += u; }
    if (lane == 63) wsum[w] = t;
    __syncthreads();
    int add = carry;
    for (int k = 0; k < w; ++k) add += wsum[k];
    if (i < Nd) rowptr[i] = t - v + add;
    __syncthreads();
    if (threadIdx.x == 0) carry += wsum[0] + wsum[1] + wsum[2] + wsum[3];
    __syncthreads();
  }
  if (threadIdx.x == 0) rowptr[Nd] = carry;
}

__global__ __launch_bounds__(256) void scatter_kernel(
    const int* __restrict__ src, const int* __restrict__ dst, int E, int nloops,
    int Nd, const int* __restrict__ offs, const int* __restrict__ rowptr,
    uint* __restrict__ sd) {
  extern __shared__ int bins[];
  int tot = E + nloops;
  int chunk = (tot + NB - 1) / NB;
  int b = blockIdx.x;
  int s0 = b * chunk, s1 = min(s0 + chunk, tot);
  for (int i = threadIdx.x; i < Nd; i += 256) bins[i] = 0;
  __syncthreads();
  for (int i = s0 + threadIdx.x; i < s1; i += 256) {
    int s_, d_;
    if (i < E) { s_ = src[i]; d_ = dst[i]; }
    else       { s_ = d_ = i - E; }
    int local = atomicAdd(&bins[d_], 1);
    int pos = rowptr[d_] + offs[(size_t)d_ * NB + b] + local;
    sd[pos] = (uint)s_ | ((uint)d_ << 16);
  }
}

// ---------------------------------------------------------------- fused GAT edge phase
template <int ACT>
__global__ __launch_bounds__(256) void gat_agg_small(
    const int* __restrict__ rowptr, const uint* __restrict__ sd,
    const float* __restrict__ als, const float* __restrict__ ald,
    const ushort* __restrict__ Hb, const float* __restrict__ bias,
    ushort* __restrict__ Ohi, ushort* __restrict__ Olo, int n) {
  int d = blockIdx.x * 4 + (threadIdx.x >> 6);
  if (d >= n) return;
  int lane = threadIdx.x & 63;
  int r0 = rowptr[d], r1 = rowptr[d + 1];
  float aldd = ald[d];
  float dsum = 0.f;
  for (int j = r0 + lane; j < r1; j += 64) {
    float e = als[sd[j] & 0xffff] + aldd;
    e = (e > 0.f) ? e : NEG_SLOPE * e;
    dsum += __expf(e);
  }
#pragma unroll
  for (int o = 32; o; o >>= 1) dsum += __shfl_xor(dsum, o);
  float rden = 1.f / (dsum + 1e-16f);

  float4 acc = make_float4(0.f, 0.f, 0.f, 0.f);
  for (int b = r0; b < r1; b += 64) {
    int j = b + lane;
    float exv = 0.f; int srcv = 0;
    if (j < r1) {
      uint p = sd[j];
      srcv = p & 0xffff;
      float e = als[srcv] + aldd;
      e = (e > 0.f) ? e : NEG_SLOPE * e;
      exv = __expf(e) * rden;
    }
    int cnt = min(64, r1 - b);
    for (int t0 = 0; t0 < cnt; t0 += 8) {
      float cf[8]; int sv[8];
#pragma unroll
      for (int u = 0; u < 8; ++u) {
        cf[u] = __shfl(exv, t0 + u);
        sv[u] = __shfl(srcv, t0 + u);
      }
      ushort4 hv[8];
#pragma unroll
      for (int u = 0; u < 8; ++u)
        hv[u] = *(const ushort4*)(Hb + (size_t)sv[u] * HDIM + lane * 4);
#pragma unroll
      for (int u = 0; u < 8; ++u) {
        acc.x += cf[u] * b2f(hv[u].x);
        acc.y += cf[u] * b2f(hv[u].y);
        acc.z += cf[u] * b2f(hv[u].z);
        acc.w += cf[u] * b2f(hv[u].w);
      }
    }
  }
  int c = lane * 4;
  float v0 = acc.x + bias[c], v1 = acc.y + bias[c + 1];
  float v2 = acc.z + bias[c + 2], v3 = acc.w + bias[c + 3];
  if (ACT == 1) {
    v0 = fmaxf(v0, 0.f); v1 = fmaxf(v1, 0.f);
    v2 = fmaxf(v2, 0.f); v3 = fmaxf(v3, 0.f);
  } else {
    float ss = v0 * v0 + v1 * v1 + v2 * v2 + v3 * v3;
#pragma unroll
    for (int o = 32; o; o >>= 1) ss += __shfl_xor(ss, o);
    float sc = 1.0f / fmaxf(sqrtf(ss), 1e-12f);
    v0 *= sc; v1 *= sc; v2 *= sc; v3 *= sc;
  }
  ushort h0, l0, h1, l1, h2, l2, h3, l3;
  f2sp(v0, h0, l0); f2sp(v1, h1, l1); f2sp(v2, h2, l2); f2sp(v3, h3, l3);
  *(ushort4*)(Ohi + (size_t)d * HDIM + c) = (ushort4){h0, h1, h2, h3};
  *(ushort4*)(Olo + (size_t)d * HDIM + c) = (ushort4){l0, l1, l2, l3};
}

__global__ __launch_bounds__(256) void gat_agg_slice(
    const int* __restrict__ rowptr, const uint* __restrict__ sd,
    const float* __restrict__ als, const float* __restrict__ ald,
    const ushort* __restrict__ Hb, float* __restrict__ out32, int n) {
  int d = blockIdx.x / SLICES;
  int sl = blockIdx.x - d * SLICES;
  if (d >= n) return;
  int lane = threadIdx.x & 63, w = threadIdx.x >> 6;
  int r0 = rowptr[d], r1 = rowptr[d + 1];
  float aldd = ald[d];
  float dsum = 0.f;
  for (int j = r0 + threadIdx.x; j < r1; j += 256) {
    float e = als[sd[j] & 0xffff] + aldd;
    e = (e > 0.f) ? e : NEG_SLOPE * e;
    dsum += __expf(e);
  }
#pragma unroll
  for (int o = 32; o; o >>= 1) dsum += __shfl_xor(dsum, o);
  __shared__ float wd[4];
  if (lane == 0) wd[w] = dsum;
  __syncthreads();
  float rden = 1.f / (wd[0] + wd[1] + wd[2] + wd[3] + 1e-16f);
  int deg = r1 - r0;
  int per_b = (deg + SLICES - 1) / SLICES;
  int b0 = r0 + sl * per_b, b1 = min(b0 + per_b, r1);
  int wdeg = b1 - b0;
  if (wdeg <= 0) return;
  int per_w = (wdeg + 3) >> 2;
  int w0 = b0 + w * per_w, w1 = min(w0 + per_w, b1);

  float4 acc = make_float4(0.f, 0.f, 0.f, 0.f);
  for (int b = w0; b < w1; b += 64) {
    int j = b + lane;
    float exv = 0.f; int srcv = 0;
    if (j < w1) {
      uint p = sd[j];
      srcv = p & 0xffff;
      float e = als[srcv] + aldd;
      e = (e > 0.f) ? e : NEG_SLOPE * e;
      exv = __expf(e) * rden;
    }
    int cnt = min(64, w1 - b);
    for (int t0 = 0; t0 < cnt; t0 += 8) {
      float cf[8]; int sv[8];
#pragma unroll
      for (int u = 0; u < 8; ++u) {
        cf[u] = __shfl(exv, t0 + u);
        sv[u] = __shfl(srcv, t0 + u);
      }
      ushort4 hv[8];
#pragma unroll
      for (int u = 0; u < 8; ++u)
        hv[u] = *(const ushort4*)(Hb + (size_t)sv[u] * HDIM + lane * 4);
#pragma unroll
      for (int u = 0; u < 8; ++u) {
        acc.x += cf[u] * b2f(hv[u].x);
        acc.y += cf[u] * b2f(hv[u].y);
        acc.z += cf[u] * b2f(hv[u].z);
        acc.w += cf[u] * b2f(hv[u].w);
      }
    }
  }
  float* o = out32 + (size_t)d * HDIM + lane * 4;
  atomicAdd(o + 0, acc.x); atomicAdd(o + 1, acc.y);
  atomicAdd(o + 2, acc.z); atomicAdd(o + 3, acc.w);
}

__global__ void finish_relu_sp(const float* __restrict__ acc, const float* __restrict__ bias,
                               ushort* __restrict__ ohi, ushort* __restrict__ olo, int total) {
  int i = blockIdx.x * blockDim.x + threadIdx.x;
  if (i >= total) return;
  int c = i & (HDIM - 1);
  float v = fmaxf(acc[i] + bias[c], 0.f);
  ushort h, l; f2sp(v, h, l);
  ohi[i] = h; olo[i] = l;
}

// ---------------------------------------------------------------- head
__global__ __launch_bounds__(256) void l2norm_sp_kernel(
    const ushort* __restrict__ ihi, const ushort* __restrict__ ilo,
    ushort* __restrict__ ohi, ushort* __restrict__ olo, int n) {
  int row = blockIdx.x * 4 + (threadIdx.x >> 6);
  if (row >= n) return;
  int lane = threadIdx.x & 63;
  float v[4];
  float ss = 0.f;
#pragma unroll
  for (int u = 0; u < 4; ++u) {
    int c = lane + u * 64;
    float t = sp2f(ihi[(size_t)row * HDIM + c], ilo[(size_t)row * HDIM + c]);
    v[u] = t;
    ss += t * t;
  }
#pragma unroll
  for (int off = 32; off; off >>= 1) ss += __shfl_xor(ss, off);
  float sc = 1.0f / fmaxf(sqrtf(ss), 1e-12f);
#pragma unroll
  for (int u = 0; u < 4; ++u) {
    int c = lane + u * 64;
    ushort h, l; f2sp(v[u] * sc, h, l);
    ohi[(size_t)row * HDIM + c] = h;
    olo[(size_t)row * HDIM + c] = l;
  }
}

__global__ __launch_bounds__(256) void head3_kernel(
    const float* __restrict__ h2, const float* __restrict__ W3, const float* __restrict__ b3,
    float* __restrict__ out, int M, int K) {
  int i = blockIdx.x * 4 + (threadIdx.x >> 6);
  int lane = threadIdx.x & 63;
  if (i >= M) return;
  float s0 = 0.f, s1 = 0.f;
  for (int k = lane; k < K; k += 64) {
    float h = h2[(size_t)i * K + k];
    s0 += h * W3[k * 2 + 0];
    s1 += h * W3[k * 2 + 1];
  }
#pragma unroll
  for (int off = 32; off; off >>= 1) {
    s0 += __shfl_down(s0, off);
    s1 += __shfl_down(s1, off);
  }
  if (lane == 0) {
    out[(size_t)i * 2 + 0] = s0 + b3[0];
    out[(size_t)i * 2 + 1] = s1 + b3[1];
  }
}

// ---------------------------------------------------------------- host side
static void build_sorted(hipStream_t stream,
                         const int* src, const int* dst, int E, int nloops, int Nd,
                         int* offs, int* binsum, int* rowptr, uint* sd) {
  size_t lds = (size_t)Nd * sizeof(int);
  hist_kernel<<<NB, 256, lds, stream>>>(src, dst, E, nloops, Nd, offs);
  scan_bins_kernel<<<cdiv(Nd, 4), 256, 0, stream>>>(offs, binsum, Nd);
  scan_base_kernel<<<1, 256, 0, stream>>>(binsum, rowptr, Nd);
  scatter_kernel<<<NB, 256, lds, stream>>>(src, dst, E, nloops, Nd, offs, rowptr, sd);
}

struct GatBufs {
  float *als, *ald, *out32;
  ushort* Hb;
};

static inline int gemm_grid(int M, int N) { return (N >> 8) * cdiv(M, 32); }

static void run_gat(hipStream_t stream,
                    const ushort* Xs_hi, const ushort* Xs_lo, int Ns,
                    const ushort* Xd_hi, const ushort* Xd_lo, int Nd, bool same,
                    const ushort* WThi, const ushort* WTlo,
                    const float* asrc, const float* adst, const float* bias,
                    const uint* sd, const int* rowptr,
                    const GatBufs& b, ushort* out_hi, ushort* out_lo, int act) {
  // src GEMM: Hb bf16 + fused dots (als, and ald too when src==dst)
  if (same) {
    gemm_dn<0, 3, 0, 2><<<gemm_grid(Ns, HDIM), 256, 0, stream>>>(
        Xs_hi, Xs_lo, nullptr, nullptr, nullptr, nullptr, nullptr, nullptr, nullptr, 0,
        WThi, WTlo, nullptr, asrc, adst, b.als, b.ald,
        nullptr, b.Hb, nullptr, nullptr, Ns, HDIM, HDIM);
  } else {
    gemm_dn<0, 3, 0, 1><<<gemm_grid(Ns, HDIM), 256, 0, stream>>>(
        Xs_hi, Xs_lo, nullptr, nullptr, nullptr, nullptr, nullptr, nullptr, nullptr, 0,
        WThi, WTlo, nullptr, asrc, nullptr, b.als, nullptr,
        nullptr, b.Hb, nullptr, nullptr, Ns, HDIM, HDIM);
    // dst GEMM: dots only (H_dst is never needed beyond ald)
    gemm_dn<0, 4, 0, 1><<<gemm_grid(Nd, HDIM), 256, 0, stream>>>(
        Xd_hi, Xd_lo, nullptr, nullptr, nullptr, nullptr, nullptr, nullptr, nullptr, 0,
        WThi, WTlo, nullptr, adst, nullptr, b.ald, nullptr,
        nullptr, nullptr, nullptr, nullptr, Nd, HDIM, HDIM);
  }
  if (Nd <= 256) {
    fillf_kernel<<<cdiv(Nd * HDIM, 256), 256, 0, stream>>>(b.out32, 0.f, Nd * HDIM);
    gat_agg_slice<<<Nd * SLICES, 256, 0, stream>>>(rowptr, sd, b.als, b.ald, b.Hb, b.out32, Nd);
    finish_relu_sp<<<cdiv(Nd * HDIM, 256), 256, 0, stream>>>(b.out32, bias, out_hi, out_lo, Nd * HDIM);
  } else if (act == 0) {
    gat_agg_small<0><<<cdiv(Nd, 4), 256, 0, stream>>>(rowptr, sd, b.als, b.ald, b.Hb, bias, out_hi, out_lo, Nd);
  } else {
    gat_agg_small<1><<<cdiv(Nd, 4), 256, 0, stream>>>(rowptr, sd, b.als, b.ald, b.Hb, bias, out_hi, out_lo, Nd);
  }
}

extern "C" void kernel_launch(void* const* d_in, const int* in_sizes, int n_in,
                              void* d_out, int out_size, void* d_ws, size_t ws_size,
                              hipStream_t stream) {
  const float* drug_emb = (const float*)d_in[0];
  const float* prot_emb = (const float*)d_in[1];
  const float* cell_emb = (const float*)d_in[2];
  const float* W_pp = (const float*)d_in[3];
  const float* as_pp = (const float*)d_in[4];
  const float* ad_pp = (const float*)d_in[5];
  const float* b_pp = (const float*)d_in[6];
  const float* W_dp = (const float*)d_in[7];
  const float* as_dp = (const float*)d_in[8];
  const float* ad_dp = (const float*)d_in[9];
  const float* b_dp = (const float*)d_in[10];
  const float* W_cp = (const float*)d_in[11];
  const float* as_cp = (const float*)d_in[12];
  const float* ad_cp = (const float*)d_in[13];
  const float* b_cp = (const float*)d_in[14];
  const float* W1 = (const float*)d_in[15];
  const float* b1 = (const float*)d_in[16];
  const float* W2 = (const float*)d_in[17];
  const float* b2 = (const float*)d_in[18];
  const float* W3 = (const float*)d_in[19];
  const float* b3 = (const float*)d_in[20];
  const int* edge_pp = (const int*)d_in[21];
  const int* edge_dp = (const int*)d_in[22];
  const int* edge_cp = (const int*)d_in[23];
  const int* drug1 = (const int*)d_in[24];
  const int* drug2 = (const int*)d_in[25];
  const int* cellb = (const int*)d_in[26];

  const int ND = in_sizes[0] / HDIM;   // 2000
  const int NP = in_sizes[1] / HDIM;   // 19000
  const int NC = in_sizes[2] / HDIM;   // 100
  const int L = in_sizes[3] / (HDIM * HDIM);  // 2
  const int E_pp = in_sizes[21] / 2;
  const int E_dp = in_sizes[22] / 2;
  const int E_cp = in_sizes[23] / 2;
  const int B = in_sizes[24];          // 8192

  const int* src_pp = edge_pp;          const int* dst_pp = edge_pp + E_pp;
  const int* src_dp = edge_dp;          const int* dst_dp = edge_dp + E_dp;
  const int* src_cp = edge_cp;          const int* dst_cp = edge_cp + E_cp;
  const int tot_pp = E_pp + NP, tot_dp = E_dp, tot_cp = E_cp;

  // ---------------- workspace
  float* ws = (float*)d_ws;
  size_t off = 0;
  auto alloc = [&](size_t n) { float* p = ws + off; off += (n + 3) & ~(size_t)3; return p; };
  auto alloc_sp = [&](size_t n, ushort*& hi, ushort*& lo) {
    float* p = alloc(n); hi = (ushort*)p; lo = hi + n;
  };
  int maxN = NP > ND ? NP : ND; if (NC > maxN) maxN = NC;

  ushort *xp_hi, *xp_lo, *xd_hi, *xd_lo, *xc_hi, *xc_lo;
  ushort *xdn_hi, *xdn_lo, *xcn_hi, *xcn_lo;
  alloc_sp((size_t)NP * HDIM, xp_hi, xp_lo);
  alloc_sp((size_t)ND * HDIM, xd_hi, xd_lo);
  alloc_sp((size_t)NC * HDIM, xc_hi, xc_lo);
  alloc_sp((size_t)ND * HDIM, xdn_hi, xdn_lo);
  alloc_sp((size_t)NC * HDIM, xcn_hi, xcn_lo);
  ushort *WTpp_hi, *WTpp_lo, *WTdp_hi, *WTdp_lo, *WTcp_hi, *WTcp_lo;
  alloc_sp((size_t)L * HDIM * HDIM, WTpp_hi, WTpp_lo);
  alloc_sp((size_t)L * HDIM * HDIM, WTdp_hi, WTdp_lo);
  alloc_sp((size_t)L * HDIM * HDIM, WTcp_hi, WTcp_lo);
  int* binsum = (int*)alloc(maxN);
  int* rp_pp = (int*)alloc(NP + 1);
  int* rp_dp = (int*)alloc(ND + 1);
  int* rp_cp = (int*)alloc(NC + 1);
  uint* sd_pp = (uint*)alloc(tot_pp);
  uint* sd_dp = (uint*)alloc(tot_dp);
  uint* sd_cp = (uint*)alloc(tot_cp);
  float* out32 = alloc((size_t)NC * HDIM);

  // scratch region S: {Hb, als, ald} <-> offs (sort) <-> MLP bufs
  size_t S0 = off;
  ushort* Hb = (ushort*)(ws + S0);                         // NP*HDIM ushorts (9.7 MB)
  float* als = (float*)(Hb + (size_t)NP * HDIM);
  float* ald = als + maxN;
  // MLP overlay (after graph phase)
  ushort* W1T_hi = (ushort*)(ws + S0);                     // 768*1536 each
  ushort* W1T_lo = W1T_hi + (size_t)768 * 1536;
  ushort* W2T_hi = W1T_lo + (size_t)768 * 1536;            // 1536*512 each
  ushort* W2T_lo = W2T_hi + (size_t)1536 * 512;
  const int CH = 4096;
  ushort* h1_hi = W2T_lo + (size_t)1536 * 512;             // CH*1536 each
  ushort* h1_lo = h1_hi + (size_t)CH * 1536;
  float* h2 = (float*)(h1_lo + (size_t)CH * 1536);         // CH*512 fp32
  (void)ws_size; (void)n_in; (void)out_size;

  // ---- sort builds (offs overlays S; dead before Hb first written)
  int* offs = (int*)(ws + S0);
  build_sorted(stream, src_pp, dst_pp, E_pp, NP, NP, offs, binsum, rp_pp, sd_pp);
  build_sorted(stream, src_dp, dst_dp, E_dp, 0, ND, offs, binsum, rp_dp, sd_dp);
  build_sorted(stream, src_cp, dst_cp, E_cp, 0, NC, offs, binsum, rp_cp, sd_cp);

  // ---- embeddings -> split hi/lo into x* (layer-0 inputs)
  split_kernel<<<cdiv(NP * HDIM, 256), 256, 0, stream>>>(prot_emb, xp_hi, xp_lo, NP * HDIM);
  split_kernel<<<cdiv(ND * HDIM, 256), 256, 0, stream>>>(drug_emb, xd_hi, xd_lo, ND * HDIM);
  split_kernel<<<cdiv(NC * HDIM, 256), 256, 0, stream>>>(cell_emb, xc_hi, xc_lo, NC * HDIM);

  // ---- graph weight splits (transposed [N][K])
  for (int l = 0; l < L; ++l) {
    int WOFF = l * HDIM * HDIM;
    wsplit_kernel<<<cdiv(HDIM * HDIM, 256), 256, 0, stream>>>(W_pp + WOFF, WTpp_hi + WOFF, WTpp_lo + WOFF, HDIM, HDIM);
    wsplit_kernel<<<cdiv(HDIM * HDIM, 256), 256, 0, stream>>>(W_dp + WOFF, WTdp_hi + WOFF, WTdp_lo + WOFF, HDIM, HDIM);
    wsplit_kernel<<<cdiv(HDIM * HDIM, 256), 256, 0, stream>>>(W_cp + WOFF, WTcp_hi + WOFF, WTcp_lo + WOFF, HDIM, HDIM);
  }

  GatBufs gb{als, ald, out32, Hb};

  for (int l = 0; l < L; ++l) {
    const int WOFF = l * HDIM * HDIM, VOFF = l * HDIM;
    run_gat(stream, xp_hi, xp_lo, NP, nullptr, nullptr, NP, /*same=*/true,
            WTpp_hi + WOFF, WTpp_lo + WOFF, as_pp + VOFF, ad_pp + VOFF, b_pp + VOFF,
            sd_pp, rp_pp, gb, xp_hi, xp_lo, 0);
    run_gat(stream, xp_hi, xp_lo, NP, xd_hi, xd_lo, ND, false,
            WTdp_hi + WOFF, WTdp_lo + WOFF, as_dp + VOFF, ad_dp + VOFF, b_dp + VOFF,
            sd_dp, rp_dp, gb, xd_hi, xd_lo, 1);
    run_gat(stream, xp_hi, xp_lo, NP, xc_hi, xc_lo, NC, false,
            WTcp_hi + WOFF, WTcp_lo + WOFF, as_cp + VOFF, ad_cp + VOFF, b_cp + VOFF,
            sd_cp, rp_cp, gb, xc_hi, xc_lo, 1);
  }

  // ---------------- head
  l2norm_sp_kernel<<<cdiv(ND, 4), 256, 0, stream>>>(xd_hi, xd_lo, xdn_hi, xdn_lo, ND);
  l2norm_sp_kernel<<<cdiv(NC, 4), 256, 0, stream>>>(xc_hi, xc_lo, xcn_hi, xcn_lo, NC);

  wsplit_kernel<<<cdiv(768 * 1536, 256), 256, 0, stream>>>(W1, W1T_hi, W1T_lo, 768, 1536);
  wsplit_kernel<<<cdiv(1536 * 512, 256), 256, 0, stream>>>(W2, W2T_hi, W2T_lo, 1536, 512);

  float* outp = (float*)d_out;
  for (int c0 = 0; c0 < B; c0 += CH) {
    int M = (B - c0) < CH ? (B - c0) : CH;
    gemm_dn<2, 1, 1, 0><<<gemm_grid(M, 1536), 256, 0, stream>>>(
        nullptr, nullptr, xdn_hi, xdn_lo, xcn_hi, xcn_lo, drug1, drug2, cellb, c0,
        W1T_hi, W1T_lo, b1, nullptr, nullptr, nullptr, nullptr,
        nullptr, nullptr, h1_hi, h1_lo, M, 1536, 768);
    gemm_dn<0, 0, 1, 0><<<gemm_grid(M, 512), 256, 0, stream>>>(
        h1_hi, h1_lo, nullptr, nullptr, nullptr, nullptr, nullptr, nullptr, nullptr, 0,
        W2T_hi, W2T_lo, b2, nullptr, nullptr, nullptr, nullptr,
        h2, nullptr, nullptr, nullptr, M, 512, 1536);
    head3_kernel<<<cdiv(M, 4), 256, 0, stream>>>(h2, W3, b3, outp + (size_t)c0 * 2, M, 512);
  }
}